// Round 5
// baseline (539.490 us; speedup 1.0000x reference)
//
#include <hip/hip_runtime.h>
#include <hip/hip_bf16.h>

typedef unsigned short u16;
typedef __attribute__((ext_vector_type(8))) short short8;
typedef __attribute__((ext_vector_type(4))) float f32x4;
typedef __attribute__((ext_vector_type(4))) unsigned short us4;
typedef __attribute__((ext_vector_type(4))) float float4v;

#define DEV __device__ __forceinline__

DEV float b2f(u16 v){ return __uint_as_float(((unsigned)v)<<16); }
DEV u16 f2b(float f){
  unsigned u = __float_as_uint(f);
  u = u + 0x7FFFu + ((u>>16)&1u);
  return (u16)(u>>16);
}
DEV f32x4 mfma16(short8 a, short8 b, f32x4 c){
  return __builtin_amdgcn_mfma_f32_16x16x32_bf16(a, b, c, 0, 0, 0);
}
DEV void async16(const void* g, const void* l){
  __builtin_amdgcn_global_load_lds(
    (const __attribute__((address_space(1))) unsigned int*)(uintptr_t)g,
    (__attribute__((address_space(3))) unsigned int*)(unsigned int)(uintptr_t)l,
    16, 0, 0);
}

// ---------------- LayerNorm (row = one token, D=1024), fp32 in -> bf16 out ----------------
__global__ __launch_bounds__(256) void ln_k(const float* __restrict__ xin,
    const float* __restrict__ g, const float* __restrict__ bb, u16* __restrict__ y)
{
  const int row = blockIdx.x, t = threadIdx.x, l = t&63, w = t>>6;
  const float4v rr = *(const float4v*)(xin + (size_t)row*1024 + t*4);
  float v[4] = {rr[0], rr[1], rr[2], rr[3]};
  float s  = v[0]+v[1]+v[2]+v[3];
  float ss = v[0]*v[0]+v[1]*v[1]+v[2]*v[2]+v[3]*v[3];
#pragma unroll
  for (int off=32; off>=1; off>>=1){
    s  += __shfl_down(s,  off, 64);
    ss += __shfl_down(ss, off, 64);
  }
  __shared__ float rs[4], rq[4];
  if (l==0){ rs[w]=s; rq[w]=ss; }
  __syncthreads();
  const float S = rs[0]+rs[1]+rs[2]+rs[3];
  const float Q = rq[0]+rq[1]+rq[2]+rq[3];
  const float mean = S*(1.0f/1024.0f);
  const float var  = Q*(1.0f/1024.0f) - mean*mean;
  const float rstd = rsqrtf(var + 1e-5f);
  const float4v gg = *(const float4v*)(g  + t*4);
  const float4v bv = *(const float4v*)(bb + t*4);
  us4 o;
#pragma unroll
  for (int j=0;j<4;j++) o[j] = f2b((v[j]-mean)*rstd*gg[j] + bv[j]);
  *(us4*)(y + (size_t)row*1024 + t*4) = o;
}

// ---------------- Weight packing: fp32 src -> bf16 BT[N][K] ----------------
__global__ void transpose_k(const float* __restrict__ src, u16* __restrict__ dst,
                            int ldsrc, int lddst)
{
  __shared__ u16 tile[32][33];
  const int tx = threadIdx.x & 31, ty = threadIdx.x >> 5;
  const int c0 = blockIdx.x*32, r0 = blockIdx.y*32;
#pragma unroll
  for (int i=0;i<32;i+=8) tile[ty+i][tx] = f2b(src[(size_t)(r0+ty+i)*ldsrc + c0+tx]);
  __syncthreads();
#pragma unroll
  for (int i=0;i<32;i+=8) dst[(size_t)(c0+ty+i)*lddst + r0+tx] = tile[tx][ty+i];
}

// wq/wk/wv: fp32 [H=16][D=1024][E=64] -> bf16 BT[(which*1024 + h*64 + e)][d]
__global__ void pack_qkv_k(const float* __restrict__ wq, const float* __restrict__ wk,
                           const float* __restrict__ wv, u16* __restrict__ BT)
{
  __shared__ u16 tile[32][33];
  const int z = blockIdx.z, which = z>>4, h = z&15;
  const float* w = (which==0?wq:(which==1?wk:wv)) + (size_t)h*1024*64;
  u16* d = BT + (size_t)(which*1024 + h*64)*1024;
  const int tx = threadIdx.x & 31, ty = threadIdx.x >> 5;
  const int c0 = blockIdx.x*32, r0 = blockIdx.y*32;   // c over E(64), r over D(1024)
#pragma unroll
  for (int i=0;i<32;i+=8) tile[ty+i][tx] = f2b(w[(size_t)(r0+ty+i)*64 + c0+tx]);
  __syncthreads();
#pragma unroll
  for (int i=0;i<32;i+=8) d[(size_t)(c0+ty+i)*1024 + r0+tx] = tile[tx][ty+i];
}

// concat fp32 biases bq|bk|bv -> biasqkv[3072]
__global__ void pack_bias_k(const float* __restrict__ bq, const float* __restrict__ bk,
                            const float* __restrict__ bv, float* __restrict__ dst)
{
  const int t = blockIdx.x*256 + threadIdx.x;   // 0..3071
  const float* s = (t < 1024) ? bq : (t < 2048 ? bk : bv);
  dst[t] = s[t & 1023];
}

// ---------------- GEMM: C[M,N] = A[M,K](bf16) * BT[N,K](bf16)^T ----------------
// EPI: 0 = +bias -> bf16 ; 1 = +bias + f32 residual -> f32 out ; 2 = +bias + GELU -> bf16
template<int EPI>
__global__ __launch_bounds__(256) void gemm_bt(
    const u16* __restrict__ A, const u16* __restrict__ BT,
    const float* __restrict__ bias, const float* __restrict__ resf,
    u16* __restrict__ outb, float* __restrict__ outf,
    int K, int lda, int ldb, int ldc)
{
  __shared__ u16 Asm[128*32];
  __shared__ u16 Bsm[128*32];
  const int t = threadIdx.x, l = t&63, w = t>>6;
  const int bn = blockIdx.x, bm = blockIdx.y;
  const u16* Ab = A  + (size_t)bm*128*lda;
  const u16* Bb = BT + (size_t)bn*128*ldb;
  const int cA = w*64 + l;
  const u16* gA = Ab + (size_t)(cA>>2)*lda + (cA&3)*8;
  const u16* gB = Bb + (size_t)(cA>>2)*ldb + (cA&3)*8;
  char* lA = (char*)Asm + w*1024;
  char* lB = (char*)Bsm + w*1024;
  const int wr = (w>>1)*64, wc = (w&1)*64;
  f32x4 acc[4][4] = {};
  for (int kt = 0; kt < K; kt += 32) {
    __syncthreads();
    async16(gA + kt,                    lA);
    async16(gA + kt + (size_t)64*lda,   lA + 4096);
    async16(gB + kt,                    lB);
    async16(gB + kt + (size_t)64*ldb,   lB + 4096);
    __syncthreads();
    short8 af[4], bf[4];
#pragma unroll
    for (int m=0;m<4;m++) af[m] = *(const short8*)&Asm[(wr + m*16 + (l&15))*32 + (l>>4)*8];
#pragma unroll
    for (int n=0;n<4;n++) bf[n] = *(const short8*)&Bsm[(wc + n*16 + (l&15))*32 + (l>>4)*8];
#pragma unroll
    for (int m=0;m<4;m++)
#pragma unroll
      for (int n=0;n<4;n++)
        acc[m][n] = mfma16(af[m], bf[n], acc[m][n]);
  }
  const int rowb = bm*128 + wr, colb = bn*128 + wc;
#pragma unroll
  for (int m=0;m<4;m++)
#pragma unroll
    for (int n=0;n<4;n++){
      const int col = colb + n*16 + (l&15);
      const float bv = bias[col];
#pragma unroll
      for (int j=0;j<4;j++){
        const int row = rowb + m*16 + (l>>4)*4 + j;
        float v = acc[m][n][j] + bv;
        const size_t idx = (size_t)row*ldc + col;
        if constexpr (EPI==0)      outb[idx] = f2b(v);
        else if constexpr (EPI==1) outf[idx] = v + resf[idx];
        else                       outb[idx] = f2b(0.5f*v*(1.0f + erff(v*0.70710678118654752f)));
      }
    }
}

// ---------------- Attention ----------------
// QKV layout: [4096 tokens][3072] with cols 0..1023=Q, 1024..2047=K, 2048..3071=V (col = h*64+e)
// Column softmax (over q): L[k] = sum_q exp(s[q,k]), s = Q.K^T / 32 (|s| small -> no max needed)

__global__ __launch_bounds__(256) void attn_stats(const u16* __restrict__ QKV, float* __restrict__ L)
{
  const int kblk = blockIdx.x, bh = blockIdx.y;
  const int b = bh>>4, h = bh&15;
  const u16* Qb = QKV + (size_t)b*2048*3072 + h*64;
  const u16* Kb = Qb + 1024;
  __shared__ u16 Klds[128*64];
  __shared__ float red[4][128];
  const int t = threadIdx.x, l = t&63, w = t>>6;
#pragma unroll
  for (int i=0;i<8;i++){
    const int c = t + i*256, r = c>>4, ch = c&15;
    us4 v = *(const us4*)(Kb + (size_t)(kblk*128 + r)*3072 + ch*4);
    *(us4*)((char*)Klds + ((r*128 + ch*8) ^ ((r&7)<<4))) = v;
  }
  __syncthreads();
  short8 kf[8][2];
#pragma unroll
  for (int n=0;n<8;n++){
    const int r = n*16 + (l&15);
    const int sw = (r&7)<<4;
#pragma unroll
    for (int ks=0;ks<2;ks++)
      kf[n][ks] = *(const short8*)((char*)Klds + ((r*128 + ks*64 + (l>>4)*16) ^ sw));
  }
  float Lacc[8] = {0,0,0,0,0,0,0,0};
  for (int qt=0; qt<16; qt++){
    const int qb = qt*128 + w*32;
    short8 qf[2][2];
#pragma unroll
    for (int m=0;m<2;m++)
#pragma unroll
      for (int ks=0;ks<2;ks++)
        qf[m][ks] = *(const short8*)(Qb + (size_t)(qb + m*16 + (l&15))*3072 + ks*32 + (l>>4)*8);
#pragma unroll
    for (int m=0;m<2;m++)
#pragma unroll
      for (int n=0;n<8;n++){
        f32x4 s = {};
        s = mfma16(qf[m][0], kf[n][0], s);
        s = mfma16(qf[m][1], kf[n][1], s);
#pragma unroll
        for (int j=0;j<4;j++) Lacc[n] += __expf(s[j]*0.03125f);
      }
  }
#pragma unroll
  for (int n=0;n<8;n++){
    Lacc[n] += __shfl_xor(Lacc[n], 16, 64);
    Lacc[n] += __shfl_xor(Lacc[n], 32, 64);
  }
  if (l < 16){
#pragma unroll
    for (int n=0;n<8;n++) red[w][n*16 + l] = Lacc[n];
  }
  __syncthreads();
  if (t < 128)
    L[(size_t)bh*2048 + kblk*128 + t] = red[0][t]+red[1][t]+red[2][t]+red[3][t];
}

__global__ __launch_bounds__(256) void attn_pv(const u16* __restrict__ QKV,
    const float* __restrict__ L, u16* __restrict__ Aout)
{
  const int qblk = blockIdx.x, bh = blockIdx.y;
  const int b = bh>>4, h = bh&15;
  const u16* Qb = QKV + (size_t)b*2048*3072 + h*64;
  const u16* Kb = Qb + 1024;
  const u16* Vb = Qb + 2048;
  const float* Lrow = L + (size_t)bh*2048;
  __shared__ u16 Klds[64*64];
  __shared__ u16 VT[64*72];
  __shared__ u16 P[128*72];
  __shared__ float invL[64];
  const int t = threadIdx.x, l = t&63, w = t>>6;
  short8 qf[2][2];
#pragma unroll
  for (int m=0;m<2;m++)
#pragma unroll
    for (int ks=0;ks<2;ks++)
      qf[m][ks] = *(const short8*)(Qb + (size_t)(qblk*128 + w*32 + m*16 + (l&15))*3072 + ks*32 + (l>>4)*8);
  f32x4 acc[2][4] = {};
  for (int kt=0; kt<2048; kt+=64){
    __syncthreads();
#pragma unroll
    for (int i=0;i<4;i++){
      const int c = t + i*256, r = c>>4, ch = c&15;
      us4 kv = *(const us4*)(Kb + (size_t)(kt + r)*3072 + ch*4);
      *(us4*)((char*)Klds + ((r*128 + ch*8) ^ ((r&7)<<4))) = kv;
      us4 vv = *(const us4*)(Vb + (size_t)(kt + r)*3072 + ch*4);
#pragma unroll
      for (int jj=0;jj<4;jj++) VT[(ch*4+jj)*72 + r] = vv[jj];
    }
    if (t < 64) invL[t] = 1.0f / Lrow[kt + t];
    __syncthreads();
    float il[4];
#pragma unroll
    for (int n=0;n<4;n++) il[n] = invL[n*16 + (l&15)];
#pragma unroll
    for (int n=0;n<4;n++){
      const int r = n*16 + (l&15);
      const int sw = (r&7)<<4;
      const short8 kf0 = *(const short8*)((char*)Klds + ((r*128 +      (l>>4)*16) ^ sw));
      const short8 kf1 = *(const short8*)((char*)Klds + ((r*128 + 64 + (l>>4)*16) ^ sw));
#pragma unroll
      for (int m=0;m<2;m++){
        f32x4 s = {};
        s = mfma16(qf[m][0], kf0, s);
        s = mfma16(qf[m][1], kf1, s);
        const int prow = w*32 + m*16 + (l>>4)*4;
        const int pcol = n*16 + (l&15);
#pragma unroll
        for (int j=0;j<4;j++)
          P[(prow+j)*72 + pcol] = f2b(__expf(s[j]*0.03125f) * il[n]);
      }
    }
    __syncthreads();   // P visible before PV reads
#pragma unroll
    for (int kk=0;kk<2;kk++){
      const short8 af0 = *(const short8*)&P[(w*32 +      (l&15))*72 + kk*32 + (l>>4)*8];
      const short8 af1 = *(const short8*)&P[(w*32 + 16 + (l&15))*72 + kk*32 + (l>>4)*8];
#pragma unroll
      for (int n=0;n<4;n++){
        const short8 bf = *(const short8*)&VT[(n*16 + (l&15))*72 + kk*32 + (l>>4)*8];
        acc[0][n] = mfma16(af0, bf, acc[0][n]);
        acc[1][n] = mfma16(af1, bf, acc[1][n]);
      }
    }
  }
  const int rowb = b*2048 + qblk*128 + w*32;
  const int colb = h*64;
#pragma unroll
  for (int m=0;m<2;m++)
#pragma unroll
    for (int n=0;n<4;n++)
#pragma unroll
      for (int j=0;j<4;j++){
        const int row = rowb + m*16 + (l>>4)*4 + j;
        const int col = colb + n*16 + (l&15);
        Aout[(size_t)row*1024 + col] = f2b(acc[m][n][j]);
      }
}

// ---------------- Host orchestration ----------------
extern "C" void kernel_launch(void* const* d_in, const int* in_sizes, int n_in,
                              void* d_out, int out_size, void* d_ws, size_t ws_size,
                              hipStream_t stream)
{
  const float* x    = (const float*)d_in[0];
  const float* ln1g = (const float*)d_in[1];
  const float* ln1b = (const float*)d_in[2];
  const float* wq   = (const float*)d_in[3];
  const float* bq   = (const float*)d_in[4];
  const float* wk   = (const float*)d_in[5];
  const float* bk   = (const float*)d_in[6];
  const float* wv   = (const float*)d_in[7];
  const float* bv   = (const float*)d_in[8];
  const float* wo   = (const float*)d_in[9];
  const float* bo   = (const float*)d_in[10];
  const float* ln2g = (const float*)d_in[11];
  const float* ln2b = (const float*)d_in[12];
  const float* w1   = (const float*)d_in[13];
  const float* b1   = (const float*)d_in[14];
  const float* w2   = (const float*)d_in[15];
  const float* b2   = (const float*)d_in[16];
  float* out = (float*)d_out;   // reference output dtype is float32

  // Workspace layout (~72.3 MiB); H1 reuses the dead QKV region.
  char* ws = (char*)d_ws;
  u16*   x1      = (u16*)  (ws + 0);             // [0, 8M)   x1 / x2
  u16*   QKV     = (u16*)  (ws + 8388608);       // [8M, 32M)  -> later H1 [8M, 40M)
  u16*   H1      = (u16*)  (ws + 8388608);
  float* Lbuf    = (float*)(ws + 41943040);      // [40M, 40.25M)
  u16*   Aout    = (u16*)  (ws + 42205184);      // [40.25M, 48.25M)
  u16*   packbuf = (u16*)  (ws + 50593792);      // [48.25M, 56.25M)
  float* inter   = (float*)(ws + 58982400);      // [56.25M, 72.25M)
  float* biasqkv = (float*)(ws + 75759616);      // [72.25M, +12K)
  u16*   x2 = x1;

  pack_bias_k<<<12, 256, 0, stream>>>(bq, bk, bv, biasqkv);

  ln_k<<<4096, 256, 0, stream>>>(x, ln1g, ln1b, x1);
  pack_qkv_k<<<dim3(2,32,48), 256, 0, stream>>>(wq, wk, wv, packbuf);
  gemm_bt<0><<<dim3(24,32), 256, 0, stream>>>(x1, packbuf, biasqkv,
      nullptr, QKV, nullptr, 1024, 1024, 1024, 3072);

  attn_stats<<<dim3(16,32), 256, 0, stream>>>(QKV, Lbuf);
  attn_pv  <<<dim3(16,32), 256, 0, stream>>>(QKV, Lbuf, Aout);

  transpose_k<<<dim3(32,32), 256, 0, stream>>>(wo, packbuf, 1024, 1024);
  gemm_bt<1><<<dim3(8,32), 256, 0, stream>>>(Aout, packbuf, bo,
      x, nullptr, inter, 1024, 1024, 1024, 1024);

  ln_k<<<4096, 256, 0, stream>>>(inter, ln2g, ln2b, x2);

  transpose_k<<<dim3(128,32), 256, 0, stream>>>(w1, packbuf, 4096, 1024);
  gemm_bt<2><<<dim3(32,32), 256, 0, stream>>>(x2, packbuf, b1,
      nullptr, H1, nullptr, 1024, 1024, 1024, 4096);

  transpose_k<<<dim3(32,128), 256, 0, stream>>>(w2, packbuf, 1024, 4096);
  gemm_bt<1><<<dim3(8,32), 256, 0, stream>>>(H1, packbuf, b2,
      inter, nullptr, out, 4096, 4096, 4096, 1024);
}

// Round 6
// 478.882 us; speedup vs baseline: 1.1266x; 1.1266x over previous
//
#include <hip/hip_runtime.h>
#include <hip/hip_bf16.h>

typedef unsigned short u16;
typedef __attribute__((ext_vector_type(8))) short short8;
typedef __attribute__((ext_vector_type(4))) float f32x4;
typedef __attribute__((ext_vector_type(4))) unsigned short us4;
typedef __attribute__((ext_vector_type(4))) float float4v;

#define DEV __device__ __forceinline__

DEV float b2f(u16 v){ return __uint_as_float(((unsigned)v)<<16); }
DEV u16 f2b(float f){
  unsigned u = __float_as_uint(f);
  u = u + 0x7FFFu + ((u>>16)&1u);
  return (u16)(u>>16);
}
DEV f32x4 mfma16(short8 a, short8 b, f32x4 c){
  return __builtin_amdgcn_mfma_f32_16x16x32_bf16(a, b, c, 0, 0, 0);
}
DEV void async16(const void* g, const void* l){
  __builtin_amdgcn_global_load_lds(
    (const __attribute__((address_space(1))) unsigned int*)(uintptr_t)g,
    (__attribute__((address_space(3))) unsigned int*)(unsigned int)(uintptr_t)l,
    16, 0, 0);
}

// ---------------- LayerNorm (row = one token, D=1024), fp32 in -> bf16 out ----------------
__global__ __launch_bounds__(256) void ln_k(const float* __restrict__ xin,
    const float* __restrict__ g, const float* __restrict__ bb, u16* __restrict__ y)
{
  const int row = blockIdx.x, t = threadIdx.x, l = t&63, w = t>>6;
  const float4v rr = *(const float4v*)(xin + (size_t)row*1024 + t*4);
  float v[4] = {rr[0], rr[1], rr[2], rr[3]};
  float s  = v[0]+v[1]+v[2]+v[3];
  float ss = v[0]*v[0]+v[1]*v[1]+v[2]*v[2]+v[3]*v[3];
#pragma unroll
  for (int off=32; off>=1; off>>=1){
    s  += __shfl_down(s,  off, 64);
    ss += __shfl_down(ss, off, 64);
  }
  __shared__ float rs[4], rq[4];
  if (l==0){ rs[w]=s; rq[w]=ss; }
  __syncthreads();
  const float S = rs[0]+rs[1]+rs[2]+rs[3];
  const float Q = rq[0]+rq[1]+rq[2]+rq[3];
  const float mean = S*(1.0f/1024.0f);
  const float var  = Q*(1.0f/1024.0f) - mean*mean;
  const float rstd = rsqrtf(var + 1e-5f);
  const float4v gg = *(const float4v*)(g  + t*4);
  const float4v bv = *(const float4v*)(bb + t*4);
  us4 o;
#pragma unroll
  for (int j=0;j<4;j++) o[j] = f2b((v[j]-mean)*rstd*gg[j] + bv[j]);
  *(us4*)(y + (size_t)row*1024 + t*4) = o;
}

// ---------------- Weight packing: fp32 src -> bf16 BT[N][K] ----------------
__global__ void transpose_k(const float* __restrict__ src, u16* __restrict__ dst,
                            int ldsrc, int lddst)
{
  __shared__ u16 tile[32][33];
  const int tx = threadIdx.x & 31, ty = threadIdx.x >> 5;
  const int c0 = blockIdx.x*32, r0 = blockIdx.y*32;
#pragma unroll
  for (int i=0;i<32;i+=8) tile[ty+i][tx] = f2b(src[(size_t)(r0+ty+i)*ldsrc + c0+tx]);
  __syncthreads();
#pragma unroll
  for (int i=0;i<32;i+=8) dst[(size_t)(c0+ty+i)*lddst + r0+tx] = tile[tx][ty+i];
}

// wq/wk/wv: fp32 [H=16][D=1024][E=64] -> bf16 BT[(which*1024 + h*64 + e)][d]
__global__ void pack_qkv_k(const float* __restrict__ wq, const float* __restrict__ wk,
                           const float* __restrict__ wv, u16* __restrict__ BT)
{
  __shared__ u16 tile[32][33];
  const int z = blockIdx.z, which = z>>4, h = z&15;
  const float* w = (which==0?wq:(which==1?wk:wv)) + (size_t)h*1024*64;
  u16* d = BT + (size_t)(which*1024 + h*64)*1024;
  const int tx = threadIdx.x & 31, ty = threadIdx.x >> 5;
  const int c0 = blockIdx.x*32, r0 = blockIdx.y*32;   // c over E(64), r over D(1024)
#pragma unroll
  for (int i=0;i<32;i+=8) tile[ty+i][tx] = f2b(w[(size_t)(r0+ty+i)*64 + c0+tx]);
  __syncthreads();
#pragma unroll
  for (int i=0;i<32;i+=8) d[(size_t)(c0+ty+i)*1024 + r0+tx] = tile[tx][ty+i];
}

// concat fp32 biases bq|bk|bv -> biasqkv[3072]
__global__ void pack_bias_k(const float* __restrict__ bq, const float* __restrict__ bk,
                            const float* __restrict__ bv, float* __restrict__ dst)
{
  const int t = blockIdx.x*256 + threadIdx.x;   // 0..3071
  const float* s = (t < 1024) ? bq : (t < 2048 ? bk : bv);
  dst[t] = s[t & 1023];
}

// ---------------- GEMM 128x128: C = A[M,K] * BT[N,K]^T ----------------
// EPI: 0 = +bias -> bf16 ; 1 = +bias + f32 residual -> f32 out ; 2 = +bias + GELU -> bf16
template<int EPI>
__global__ __launch_bounds__(256) void gemm_bt(
    const u16* __restrict__ A, const u16* __restrict__ BT,
    const float* __restrict__ bias, const float* __restrict__ resf,
    u16* __restrict__ outb, float* __restrict__ outf,
    int K, int lda, int ldb, int ldc)
{
  __shared__ u16 Asm[128*32];
  __shared__ u16 Bsm[128*32];
  const int t = threadIdx.x, l = t&63, w = t>>6;
  const int bn = blockIdx.x, bm = blockIdx.y;
  const u16* gA = A  + (size_t)(bm*128 + (t>>2))*lda + (t&3)*8;
  const u16* gB = BT + (size_t)(bn*128 + (t>>2))*ldb + (t&3)*8;
  char* lA = (char*)Asm + t*16;
  char* lB = (char*)Bsm + t*16;
  const int wr = (w>>1)*64, wc = (w&1)*64;
  f32x4 acc[4][4] = {};
  for (int kt = 0; kt < K; kt += 32) {
    __syncthreads();
    async16(gA + kt,                    lA);
    async16(gA + kt + (size_t)64*lda,   lA + 4096);
    async16(gB + kt,                    lB);
    async16(gB + kt + (size_t)64*ldb,   lB + 4096);
    __syncthreads();
    short8 af[4], bf[4];
#pragma unroll
    for (int m=0;m<4;m++) af[m] = *(const short8*)&Asm[(wr + m*16 + (l&15))*32 + (l>>4)*8];
#pragma unroll
    for (int n=0;n<4;n++) bf[n] = *(const short8*)&Bsm[(wc + n*16 + (l&15))*32 + (l>>4)*8];
#pragma unroll
    for (int m=0;m<4;m++)
#pragma unroll
      for (int n=0;n<4;n++)
        acc[m][n] = mfma16(af[m], bf[n], acc[m][n]);
  }
  const int rowb = bm*128 + wr, colb = bn*128 + wc;
#pragma unroll
  for (int m=0;m<4;m++)
#pragma unroll
    for (int n=0;n<4;n++){
      const int col = colb + n*16 + (l&15);
      const float bv = bias[col];
#pragma unroll
      for (int j=0;j<4;j++){
        const int row = rowb + m*16 + (l>>4)*4 + j;
        float v = acc[m][n][j] + bv;
        const size_t idx = (size_t)row*ldc + col;
        if constexpr (EPI==0)      outb[idx] = f2b(v);
        else if constexpr (EPI==1) outf[idx] = v + resf[idx];
        else                       outb[idx] = f2b(0.5f*v*(1.0f + erff(v*0.70710678118654752f)));
      }
    }
}

// ---------------- GEMM 128x64 tile (2x grid for small-N GEMMs) ----------------
// EPI 1 only used: +bias + f32 residual -> f32 out
template<int EPI>
__global__ __launch_bounds__(256) void gemm_bt64(
    const u16* __restrict__ A, const u16* __restrict__ BT,
    const float* __restrict__ bias, const float* __restrict__ resf,
    u16* __restrict__ outb, float* __restrict__ outf,
    int K, int lda, int ldb, int ldc)
{
  __shared__ u16 Asm[128*32];
  __shared__ u16 Bsm[64*32];
  const int t = threadIdx.x, l = t&63, w = t>>6;
  const int bn = blockIdx.x, bm = blockIdx.y;
  const u16* gA = A  + (size_t)(bm*128 + (t>>2))*lda + (t&3)*8;
  const u16* gB = BT + (size_t)(bn*64  + (t>>2))*ldb + (t&3)*8;
  char* lA = (char*)Asm + t*16;
  char* lB = (char*)Bsm + t*16;
  const int wr = w*32;          // wave m-offset (4 waves x 32 rows)
  f32x4 acc[2][4] = {};
  for (int kt = 0; kt < K; kt += 32) {
    __syncthreads();
    async16(gA + kt,                    lA);
    async16(gA + kt + (size_t)64*lda,   lA + 4096);
    async16(gB + kt,                    lB);
    __syncthreads();
    short8 af[2], bf[4];
#pragma unroll
    for (int m=0;m<2;m++) af[m] = *(const short8*)&Asm[(wr + m*16 + (l&15))*32 + (l>>4)*8];
#pragma unroll
    for (int n=0;n<4;n++) bf[n] = *(const short8*)&Bsm[(n*16 + (l&15))*32 + (l>>4)*8];
#pragma unroll
    for (int m=0;m<2;m++)
#pragma unroll
      for (int n=0;n<4;n++)
        acc[m][n] = mfma16(af[m], bf[n], acc[m][n]);
  }
  const int rowb = bm*128 + wr, colb = bn*64;
#pragma unroll
  for (int m=0;m<2;m++)
#pragma unroll
    for (int n=0;n<4;n++){
      const int col = colb + n*16 + (l&15);
      const float bv = bias[col];
#pragma unroll
      for (int j=0;j<4;j++){
        const int row = rowb + m*16 + (l>>4)*4 + j;
        float v = acc[m][n][j] + bv;
        const size_t idx = (size_t)row*ldc + col;
        if constexpr (EPI==0)      outb[idx] = f2b(v);
        else if constexpr (EPI==1) outf[idx] = v + resf[idx];
        else                       outb[idx] = f2b(0.5f*v*(1.0f + erff(v*0.70710678118654752f)));
      }
    }
}

// ---------------- Attention ----------------
// QKV layout: [4096 tokens][3072], cols 0..1023=Q, 1024..2047=K, 2048..3071=V (col = h*64+e)
// Column softmax (over q): L[k] = sum_q exp(s[q,k]), s = Q.K^T / 32 (|s| small -> no max needed)
// L computed in two q-halves (part 0/1) for occupancy; pv sums both partials.

__global__ __launch_bounds__(256) void attn_stats(const u16* __restrict__ QKV, float* __restrict__ L)
{
  // XCD-aware swizzle: each XCD owns 4 heads entirely
  const int g = blockIdx.x;                 // 0..1023
  const int xcd = g & 7, s_ = g >> 3;       // s_ 0..127
  const int bh   = xcd*4 + (s_ & 3);
  const int kblk = (s_ >> 2) & 15;
  const int part = s_ >> 6;                 // 0/1
  const int b = bh>>4, h = bh&15;
  const u16* Qb = QKV + (size_t)b*2048*3072 + h*64;
  const u16* Kb = Qb + 1024;
  __shared__ u16 Klds[128*64];
  __shared__ float red[4][128];
  const int t = threadIdx.x, l = t&63, w = t>>6;
#pragma unroll
  for (int i=0;i<8;i++){
    const int c = t + i*256, r = c>>4, ch = c&15;
    us4 v = *(const us4*)(Kb + (size_t)(kblk*128 + r)*3072 + ch*4);
    *(us4*)((char*)Klds + ((r*128 + ch*8) ^ ((r&7)<<4))) = v;
  }
  __syncthreads();
  short8 kf[8][2];
#pragma unroll
  for (int n=0;n<8;n++){
    const int r = n*16 + (l&15);
    const int sw = (r&7)<<4;
#pragma unroll
    for (int ks=0;ks<2;ks++)
      kf[n][ks] = *(const short8*)((char*)Klds + ((r*128 + ks*64 + (l>>4)*16) ^ sw));
  }
  float Lacc[8] = {0,0,0,0,0,0,0,0};
  for (int qt = part*8; qt < part*8 + 8; qt++){
    const int qb = qt*128 + w*32;
    short8 qf[2][2];
#pragma unroll
    for (int m=0;m<2;m++)
#pragma unroll
      for (int ks=0;ks<2;ks++)
        qf[m][ks] = *(const short8*)(Qb + (size_t)(qb + m*16 + (l&15))*3072 + ks*32 + (l>>4)*8);
#pragma unroll
    for (int m=0;m<2;m++)
#pragma unroll
      for (int n=0;n<8;n++){
        f32x4 s = {};
        s = mfma16(qf[m][0], kf[n][0], s);
        s = mfma16(qf[m][1], kf[n][1], s);
#pragma unroll
        for (int j=0;j<4;j++) Lacc[n] += __expf(s[j]*0.03125f);
      }
  }
#pragma unroll
  for (int n=0;n<8;n++){
    Lacc[n] += __shfl_xor(Lacc[n], 16, 64);
    Lacc[n] += __shfl_xor(Lacc[n], 32, 64);
  }
  if (l < 16){
#pragma unroll
    for (int n=0;n<8;n++) red[w][n*16 + l] = Lacc[n];
  }
  __syncthreads();
  if (t < 128)
    L[(size_t)part*65536 + (size_t)bh*2048 + kblk*128 + t]
        = red[0][t]+red[1][t]+red[2][t]+red[3][t];
}

__global__ __launch_bounds__(256) void attn_pv(const u16* __restrict__ QKV,
    const float* __restrict__ L, u16* __restrict__ Aout)
{
  // XCD-aware swizzle: each XCD owns 4 heads entirely
  const int g = blockIdx.x;                // 0..1023
  const int xcd = g & 7, s_ = g >> 3;      // s_ 0..127
  const int bh = xcd*4 + (s_ & 3);
  const int qblk = s_ >> 2;                // 0..31 (64 q-rows each)
  const int b = bh>>4, h = bh&15;
  const u16* Qb = QKV + (size_t)b*2048*3072 + h*64;
  const u16* Kb = Qb + 1024;
  const u16* Vb = Qb + 2048;
  const float* L0 = L + (size_t)bh*2048;
  const float* L1 = L0 + 65536;
  __shared__ u16 Klds[64*64];
  __shared__ u16 VT[64*66];     // stride 66 u16 = 132 B (bank step 1)
  __shared__ u16 P[64*68];      // stride 68 u16 = 136 B (bank step 2)
  __shared__ float invL[64];
  const int t = threadIdx.x, l = t&63, w = t>>6;
  short8 qf[2];
#pragma unroll
  for (int ks=0;ks<2;ks++)
    qf[ks] = *(const short8*)(Qb + (size_t)(qblk*64 + w*16 + (l&15))*3072 + ks*32 + (l>>4)*8);
  f32x4 acc[4] = {};
  for (int kt=0; kt<2048; kt+=64){
    __syncthreads();
#pragma unroll
    for (int i=0;i<4;i++){
      const int c = t + i*256, r = c>>4, ch = c&15;
      us4 kv = *(const us4*)(Kb + (size_t)(kt + r)*3072 + ch*4);
      *(us4*)((char*)Klds + ((r*128 + ch*8) ^ ((r&7)<<4))) = kv;
      us4 vv = *(const us4*)(Vb + (size_t)(kt + r)*3072 + ch*4);
#pragma unroll
      for (int jj=0;jj<4;jj++) VT[(ch*4+jj)*66 + r] = vv[jj];
    }
    if (t < 64) invL[t] = 1.0f / (L0[kt + t] + L1[kt + t]);
    __syncthreads();
    float il[4];
#pragma unroll
    for (int n=0;n<4;n++) il[n] = invL[n*16 + (l&15)];
#pragma unroll
    for (int n=0;n<4;n++){
      const int r = n*16 + (l&15);
      const int sw = (r&7)<<4;
      const short8 kf0 = *(const short8*)((char*)Klds + ((r*128 +      (l>>4)*16) ^ sw));
      const short8 kf1 = *(const short8*)((char*)Klds + ((r*128 + 64 + (l>>4)*16) ^ sw));
      f32x4 s = {};
      s = mfma16(qf[0], kf0, s);
      s = mfma16(qf[1], kf1, s);
      const int prow = w*16 + (l>>4)*4;
      const int pcol = n*16 + (l&15);
#pragma unroll
      for (int j=0;j<4;j++)
        P[(prow+j)*68 + pcol] = f2b(__expf(s[j]*0.03125f) * il[n]);
    }
    __syncthreads();   // P/VT visible before PV reads
#pragma unroll
    for (int kk=0;kk<2;kk++){
      const short8 af = *(const short8*)&P[(w*16 + (l&15))*68 + kk*32 + (l>>4)*8];
#pragma unroll
      for (int n=0;n<4;n++){
        const short8 bf = *(const short8*)&VT[(n*16 + (l&15))*66 + kk*32 + (l>>4)*8];
        acc[n] = mfma16(af, bf, acc[n]);
      }
    }
  }
  const int rowb = b*2048 + qblk*64 + w*16;
  const int colb = h*64;
#pragma unroll
  for (int n=0;n<4;n++)
#pragma unroll
    for (int j=0;j<4;j++){
      const int row = rowb + (l>>4)*4 + j;
      const int col = colb + n*16 + (l&15);
      Aout[(size_t)row*1024 + col] = f2b(acc[n][j]);
    }
}

// ---------------- Host orchestration ----------------
extern "C" void kernel_launch(void* const* d_in, const int* in_sizes, int n_in,
                              void* d_out, int out_size, void* d_ws, size_t ws_size,
                              hipStream_t stream)
{
  const float* x    = (const float*)d_in[0];
  const float* ln1g = (const float*)d_in[1];
  const float* ln1b = (const float*)d_in[2];
  const float* wq   = (const float*)d_in[3];
  const float* bq   = (const float*)d_in[4];
  const float* wk   = (const float*)d_in[5];
  const float* bk   = (const float*)d_in[6];
  const float* wv   = (const float*)d_in[7];
  const float* bv   = (const float*)d_in[8];
  const float* wo   = (const float*)d_in[9];
  const float* bo   = (const float*)d_in[10];
  const float* ln2g = (const float*)d_in[11];
  const float* ln2b = (const float*)d_in[12];
  const float* w1   = (const float*)d_in[13];
  const float* b1   = (const float*)d_in[14];
  const float* w2   = (const float*)d_in[15];
  const float* b2   = (const float*)d_in[16];
  float* out = (float*)d_out;   // reference output dtype is float32

  // Workspace layout (~72.6 MiB)
  char* ws = (char*)d_ws;
  u16*   x1      = (u16*)  (ws + 0);             // [0, 8M)   x1 / x2
  u16*   QKV     = (u16*)  (ws + 8388608);       // [8M, 32M)  -> later H1 [8M, 40M)
  u16*   H1      = (u16*)  (ws + 8388608);
  float* Lbuf    = (float*)(ws + 41943040);      // [40M, +512K)  2 partials
  u16*   Aout    = (u16*)  (ws + 42467328);      // +8M
  u16*   packbuf = (u16*)  (ws + 50855936);      // +8M
  float* inter   = (float*)(ws + 59244544);      // +16M
  float* biasqkv = (float*)(ws + 76021760);      // +12K
  u16*   x2 = x1;

  pack_bias_k<<<12, 256, 0, stream>>>(bq, bk, bv, biasqkv);

  ln_k<<<4096, 256, 0, stream>>>(x, ln1g, ln1b, x1);
  pack_qkv_k<<<dim3(2,32,48), 256, 0, stream>>>(wq, wk, wv, packbuf);
  gemm_bt<0><<<dim3(24,32), 256, 0, stream>>>(x1, packbuf, biasqkv,
      nullptr, QKV, nullptr, 1024, 1024, 1024, 3072);

  attn_stats<<<1024, 256, 0, stream>>>(QKV, Lbuf);
  attn_pv  <<<1024, 256, 0, stream>>>(QKV, Lbuf, Aout);

  transpose_k<<<dim3(32,32), 256, 0, stream>>>(wo, packbuf, 1024, 1024);
  gemm_bt64<1><<<dim3(16,32), 256, 0, stream>>>(Aout, packbuf, bo,
      x, nullptr, inter, 1024, 1024, 1024, 1024);

  ln_k<<<4096, 256, 0, stream>>>(inter, ln2g, ln2b, x2);

  transpose_k<<<dim3(128,32), 256, 0, stream>>>(w1, packbuf, 4096, 1024);
  gemm_bt<2><<<dim3(32,32), 256, 0, stream>>>(x2, packbuf, b1,
      nullptr, H1, nullptr, 1024, 1024, 1024, 4096);

  transpose_k<<<dim3(32,128), 256, 0, stream>>>(w2, packbuf, 1024, 4096);
  gemm_bt64<1><<<dim3(16,32), 256, 0, stream>>>(H1, packbuf, b2,
      inter, nullptr, out, 4096, 4096, 4096, 1024);
}

// Round 7
// 476.923 us; speedup vs baseline: 1.1312x; 1.0041x over previous
//
#include <hip/hip_runtime.h>
#include <hip/hip_bf16.h>

typedef unsigned short u16;
typedef __attribute__((ext_vector_type(8))) short short8;
typedef __attribute__((ext_vector_type(4))) float f32x4;
typedef __attribute__((ext_vector_type(4))) unsigned short us4;
typedef __attribute__((ext_vector_type(4))) float float4v;

#define DEV __device__ __forceinline__

DEV float b2f(u16 v){ return __uint_as_float(((unsigned)v)<<16); }
DEV u16 f2b(float f){
  unsigned u = __float_as_uint(f);
  u = u + 0x7FFFu + ((u>>16)&1u);
  return (u16)(u>>16);
}
DEV f32x4 mfma16(short8 a, short8 b, f32x4 c){
  return __builtin_amdgcn_mfma_f32_16x16x32_bf16(a, b, c, 0, 0, 0);
}
DEV void async16(const void* g, const void* l){
  __builtin_amdgcn_global_load_lds(
    (const __attribute__((address_space(1))) unsigned int*)(uintptr_t)g,
    (__attribute__((address_space(3))) unsigned int*)(unsigned int)(uintptr_t)l,
    16, 0, 0);
}

// ---------------- LayerNorm (row = one token, D=1024), fp32 in -> bf16 out ----------------
__global__ __launch_bounds__(256) void ln_k(const float* __restrict__ xin,
    const float* __restrict__ g, const float* __restrict__ bb, u16* __restrict__ y)
{
  const int row = blockIdx.x, t = threadIdx.x, l = t&63, w = t>>6;
  const float4v rr = *(const float4v*)(xin + (size_t)row*1024 + t*4);
  float v[4] = {rr[0], rr[1], rr[2], rr[3]};
  float s  = v[0]+v[1]+v[2]+v[3];
  float ss = v[0]*v[0]+v[1]*v[1]+v[2]*v[2]+v[3]*v[3];
#pragma unroll
  for (int off=32; off>=1; off>>=1){
    s  += __shfl_down(s,  off, 64);
    ss += __shfl_down(ss, off, 64);
  }
  __shared__ float rs[4], rq[4];
  if (l==0){ rs[w]=s; rq[w]=ss; }
  __syncthreads();
  const float S = rs[0]+rs[1]+rs[2]+rs[3];
  const float Q = rq[0]+rq[1]+rq[2]+rq[3];
  const float mean = S*(1.0f/1024.0f);
  const float var  = Q*(1.0f/1024.0f) - mean*mean;
  const float rstd = rsqrtf(var + 1e-5f);
  const float4v gg = *(const float4v*)(g  + t*4);
  const float4v bv = *(const float4v*)(bb + t*4);
  us4 o;
#pragma unroll
  for (int j=0;j<4;j++) o[j] = f2b((v[j]-mean)*rstd*gg[j] + bv[j]);
  *(us4*)(y + (size_t)row*1024 + t*4) = o;
}

// ---------------- Weight packing: fp32 src -> bf16 BT[N][K] ----------------
__global__ void transpose_k(const float* __restrict__ src, u16* __restrict__ dst,
                            int ldsrc, int lddst)
{
  __shared__ u16 tile[32][33];
  const int tx = threadIdx.x & 31, ty = threadIdx.x >> 5;
  const int c0 = blockIdx.x*32, r0 = blockIdx.y*32;
#pragma unroll
  for (int i=0;i<32;i+=8) tile[ty+i][tx] = f2b(src[(size_t)(r0+ty+i)*ldsrc + c0+tx]);
  __syncthreads();
#pragma unroll
  for (int i=0;i<32;i+=8) dst[(size_t)(c0+ty+i)*lddst + r0+tx] = tile[tx][ty+i];
}

// wq/wk/wv: fp32 [H=16][D=1024][E=64] -> bf16 BT[(which*1024 + h*64 + e)][d]
__global__ void pack_qkv_k(const float* __restrict__ wq, const float* __restrict__ wk,
                           const float* __restrict__ wv, u16* __restrict__ BT)
{
  __shared__ u16 tile[32][33];
  const int z = blockIdx.z, which = z>>4, h = z&15;
  const float* w = (which==0?wq:(which==1?wk:wv)) + (size_t)h*1024*64;
  u16* d = BT + (size_t)(which*1024 + h*64)*1024;
  const int tx = threadIdx.x & 31, ty = threadIdx.x >> 5;
  const int c0 = blockIdx.x*32, r0 = blockIdx.y*32;   // c over E(64), r over D(1024)
#pragma unroll
  for (int i=0;i<32;i+=8) tile[ty+i][tx] = f2b(w[(size_t)(r0+ty+i)*64 + c0+tx]);
  __syncthreads();
#pragma unroll
  for (int i=0;i<32;i+=8) d[(size_t)(c0+ty+i)*1024 + r0+tx] = tile[tx][ty+i];
}

// concat fp32 biases bq|bk|bv -> biasqkv[3072]
__global__ void pack_bias_k(const float* __restrict__ bq, const float* __restrict__ bk,
                            const float* __restrict__ bv, float* __restrict__ dst)
{
  const int t = blockIdx.x*256 + threadIdx.x;   // 0..3071
  const float* s = (t < 1024) ? bq : (t < 2048 ? bk : bv);
  dst[t] = s[t & 1023];
}

// invL[i] = 1 / (Lpart0[i] + Lpart1[i]) ; 65536 elems
__global__ __launch_bounds__(256) void inv_l(const float* __restrict__ L, float* __restrict__ invL)
{
  const int i = blockIdx.x*256 + threadIdx.x;
  invL[i] = 1.0f / (L[i] + L[i + 65536]);
}

// ---------------- GEMM 128x128: C = A[M,K] * BT[N,K]^T ----------------
// EPI: 0 = +bias -> bf16 ; 1 = +bias + f32 residual -> f32 out ; 2 = +bias + GELU -> bf16
template<int EPI>
__global__ __launch_bounds__(256) void gemm_bt(
    const u16* __restrict__ A, const u16* __restrict__ BT,
    const float* __restrict__ bias, const float* __restrict__ resf,
    u16* __restrict__ outb, float* __restrict__ outf,
    int K, int lda, int ldb, int ldc)
{
  __shared__ u16 Asm[128*32];
  __shared__ u16 Bsm[128*32];
  const int t = threadIdx.x, l = t&63, w = t>>6;
  const int bn = blockIdx.x, bm = blockIdx.y;
  const u16* gA = A  + (size_t)(bm*128 + (t>>2))*lda + (t&3)*8;
  const u16* gB = BT + (size_t)(bn*128 + (t>>2))*ldb + (t&3)*8;
  char* lA = (char*)Asm + t*16;
  char* lB = (char*)Bsm + t*16;
  const int wr = (w>>1)*64, wc = (w&1)*64;
  f32x4 acc[4][4] = {};
  for (int kt = 0; kt < K; kt += 32) {
    __syncthreads();
    async16(gA + kt,                    lA);
    async16(gA + kt + (size_t)64*lda,   lA + 4096);
    async16(gB + kt,                    lB);
    async16(gB + kt + (size_t)64*ldb,   lB + 4096);
    __syncthreads();
    short8 af[4], bf[4];
#pragma unroll
    for (int m=0;m<4;m++) af[m] = *(const short8*)&Asm[(wr + m*16 + (l&15))*32 + (l>>4)*8];
#pragma unroll
    for (int n=0;n<4;n++) bf[n] = *(const short8*)&Bsm[(wc + n*16 + (l&15))*32 + (l>>4)*8];
#pragma unroll
    for (int m=0;m<4;m++)
#pragma unroll
      for (int n=0;n<4;n++)
        acc[m][n] = mfma16(af[m], bf[n], acc[m][n]);
  }
  const int rowb = bm*128 + wr, colb = bn*128 + wc;
#pragma unroll
  for (int m=0;m<4;m++)
#pragma unroll
    for (int n=0;n<4;n++){
      const int col = colb + n*16 + (l&15);
      const float bv = bias[col];
#pragma unroll
      for (int j=0;j<4;j++){
        const int row = rowb + m*16 + (l>>4)*4 + j;
        float v = acc[m][n][j] + bv;
        const size_t idx = (size_t)row*ldc + col;
        if constexpr (EPI==0)      outb[idx] = f2b(v);
        else if constexpr (EPI==1) outf[idx] = v + resf[idx];
        else                       outb[idx] = f2b(0.5f*v*(1.0f + erff(v*0.70710678118654752f)));
      }
    }
}

// ---------------- GEMM 128x64 tile (2x grid for small-N GEMMs) ----------------
template<int EPI>
__global__ __launch_bounds__(256) void gemm_bt64(
    const u16* __restrict__ A, const u16* __restrict__ BT,
    const float* __restrict__ bias, const float* __restrict__ resf,
    u16* __restrict__ outb, float* __restrict__ outf,
    int K, int lda, int ldb, int ldc)
{
  __shared__ u16 Asm[128*32];
  __shared__ u16 Bsm[64*32];
  const int t = threadIdx.x, l = t&63, w = t>>6;
  const int bn = blockIdx.x, bm = blockIdx.y;
  const u16* gA = A  + (size_t)(bm*128 + (t>>2))*lda + (t&3)*8;
  const u16* gB = BT + (size_t)(bn*64  + (t>>2))*ldb + (t&3)*8;
  char* lA = (char*)Asm + t*16;
  char* lB = (char*)Bsm + t*16;
  const int wr = w*32;
  f32x4 acc[2][4] = {};
  for (int kt = 0; kt < K; kt += 32) {
    __syncthreads();
    async16(gA + kt,                    lA);
    async16(gA + kt + (size_t)64*lda,   lA + 4096);
    async16(gB + kt,                    lB);
    __syncthreads();
    short8 af[2], bf[4];
#pragma unroll
    for (int m=0;m<2;m++) af[m] = *(const short8*)&Asm[(wr + m*16 + (l&15))*32 + (l>>4)*8];
#pragma unroll
    for (int n=0;n<4;n++) bf[n] = *(const short8*)&Bsm[(n*16 + (l&15))*32 + (l>>4)*8];
#pragma unroll
    for (int m=0;m<2;m++)
#pragma unroll
      for (int n=0;n<4;n++)
        acc[m][n] = mfma16(af[m], bf[n], acc[m][n]);
  }
  const int rowb = bm*128 + wr, colb = bn*64;
#pragma unroll
  for (int m=0;m<2;m++)
#pragma unroll
    for (int n=0;n<4;n++){
      const int col = colb + n*16 + (l&15);
      const float bv = bias[col];
#pragma unroll
      for (int j=0;j<4;j++){
        const int row = rowb + m*16 + (l>>4)*4 + j;
        float v = acc[m][n][j] + bv;
        const size_t idx = (size_t)row*ldc + col;
        if constexpr (EPI==0)      outb[idx] = f2b(v);
        else if constexpr (EPI==1) outf[idx] = v + resf[idx];
        else                       outb[idx] = f2b(0.5f*v*(1.0f + erff(v*0.70710678118654752f)));
      }
    }
}

// ---------------- Attention ----------------
// QKV layout: [4096 tokens][3072], cols 0..1023=Q, 1024..2047=K, 2048..3071=V (col = h*64+e)
// Column softmax (over q): L[k] = sum_q exp(s[q,k]), s = Q.K^T / 32.

__global__ __launch_bounds__(256) void attn_stats(const u16* __restrict__ QKV, float* __restrict__ L)
{
  const int g = blockIdx.x;                 // 0..1023, XCD-swizzled
  const int xcd = g & 7, s_ = g >> 3;
  const int bh   = xcd*4 + (s_ & 3);
  const int kblk = (s_ >> 2) & 15;
  const int part = s_ >> 6;                 // 0/1
  const int b = bh>>4, h = bh&15;
  const u16* Qb = QKV + (size_t)b*2048*3072 + h*64;
  const u16* Kb = Qb + 1024;
  __shared__ u16 Klds[128*64];
  __shared__ float red[4][128];
  const int t = threadIdx.x, l = t&63, w = t>>6;
#pragma unroll
  for (int i=0;i<8;i++){
    const int c = t + i*256, r = c>>4, ch = c&15;
    us4 v = *(const us4*)(Kb + (size_t)(kblk*128 + r)*3072 + ch*4);
    *(us4*)((char*)Klds + ((r*128 + ch*8) ^ ((r&7)<<4))) = v;
  }
  __syncthreads();
  short8 kf[8][2];
#pragma unroll
  for (int n=0;n<8;n++){
    const int r = n*16 + (l&15);
    const int sw = (r&7)<<4;
#pragma unroll
    for (int ks=0;ks<2;ks++)
      kf[n][ks] = *(const short8*)((char*)Klds + ((r*128 + ks*64 + (l>>4)*16) ^ sw));
  }
  float Lacc[8] = {0,0,0,0,0,0,0,0};
  short8 qf[2][2], qn[2][2];
  {
    const int qb = part*1024 + w*32;
#pragma unroll
    for (int m=0;m<2;m++)
#pragma unroll
      for (int ks=0;ks<2;ks++)
        qf[m][ks] = *(const short8*)(Qb + (size_t)(qb + m*16 + (l&15))*3072 + ks*32 + (l>>4)*8);
  }
  for (int qt = 0; qt < 8; qt++){
    if (qt < 7){
      const int qb = part*1024 + (qt+1)*128 + w*32;
#pragma unroll
      for (int m=0;m<2;m++)
#pragma unroll
        for (int ks=0;ks<2;ks++)
          qn[m][ks] = *(const short8*)(Qb + (size_t)(qb + m*16 + (l&15))*3072 + ks*32 + (l>>4)*8);
    }
#pragma unroll
    for (int m=0;m<2;m++)
#pragma unroll
      for (int n=0;n<8;n++){
        f32x4 s = {};
        s = mfma16(qf[m][0], kf[n][0], s);
        s = mfma16(qf[m][1], kf[n][1], s);
#pragma unroll
        for (int j=0;j<4;j++) Lacc[n] += __expf(s[j]*0.03125f);
      }
    if (qt < 7){
#pragma unroll
      for (int m=0;m<2;m++)
#pragma unroll
        for (int ks=0;ks<2;ks++) qf[m][ks] = qn[m][ks];
    }
  }
#pragma unroll
  for (int n=0;n<8;n++){
    Lacc[n] += __shfl_xor(Lacc[n], 16, 64);
    Lacc[n] += __shfl_xor(Lacc[n], 32, 64);
  }
  if (l < 16){
#pragma unroll
    for (int n=0;n<8;n++) red[w][n*16 + l] = Lacc[n];
  }
  __syncthreads();
  if (t < 128)
    L[(size_t)part*65536 + (size_t)bh*2048 + kblk*128 + t]
        = red[0][t]+red[1][t]+red[2][t]+red[3][t];
}

// 2-barrier pipelined PV: K/V/invL prefetched to regs one tile ahead.
__global__ __launch_bounds__(256) void attn_pv(const u16* __restrict__ QKV,
    const float* __restrict__ invL, u16* __restrict__ Aout)
{
  const int g = blockIdx.x;                // 0..1023, XCD-swizzled
  const int xcd = g & 7, s_ = g >> 3;
  const int bh = xcd*4 + (s_ & 3);
  const int qblk = s_ >> 2;                // 0..31 (64 q-rows each)
  const int b = bh>>4, h = bh&15;
  const u16* Qb = QKV + (size_t)b*2048*3072 + h*64;
  const u16* Kb = Qb + 1024;
  const u16* Vb = Qb + 2048;
  const float* iL = invL + (size_t)bh*2048;
  __shared__ u16 Klds[64*64];
  __shared__ u16 VT[64*66];     // [e][k], stride 66
  __shared__ u16 P[64*68];      // [q][k], stride 68
  __shared__ float iLs[64];
  const int t = threadIdx.x, l = t&63, w = t>>6;
  short8 qf[2];
#pragma unroll
  for (int ks=0;ks<2;ks++)
    qf[ks] = *(const short8*)(Qb + (size_t)(qblk*64 + w*16 + (l&15))*3072 + ks*32 + (l>>4)*8);
  int rr[4], cc[4];
#pragma unroll
  for (int i=0;i<4;i++){ const int c = t + i*256; rr[i] = c>>4; cc[i] = c&15; }
  us4 kreg[4], vreg[4];
#pragma unroll
  for (int i=0;i<4;i++){
    kreg[i] = *(const us4*)(Kb + (size_t)rr[i]*3072 + cc[i]*4);
    vreg[i] = *(const us4*)(Vb + (size_t)rr[i]*3072 + cc[i]*4);
  }
  float ilreg = (t < 64) ? iL[t] : 0.0f;
  f32x4 acc[4] = {};
  for (int kt=0; kt<2048; kt+=64){
    // stage K (swizzled) + invL from regs (tile t)
#pragma unroll
    for (int i=0;i<4;i++)
      *(us4*)((char*)Klds + ((rr[i]*128 + cc[i]*8) ^ ((rr[i]&7)<<4))) = kreg[i];
    if (t < 64) iLs[t] = ilreg;
    __syncthreads();                               // B1: K/iL visible; prev-iter P/VT readers done
    // stage VT (transpose) from vreg (tile t)
#pragma unroll
    for (int i=0;i<4;i++){
#pragma unroll
      for (int jj=0;jj<4;jj++) VT[(cc[i]*4+jj)*66 + rr[i]] = vreg[i][jj];
    }
    // prefetch tile t+1 (latency hidden under softmax+PV below)
    if (kt + 64 < 2048){
      const u16* Kn = Kb + (size_t)(kt+64)*3072;
      const u16* Vn = Vb + (size_t)(kt+64)*3072;
#pragma unroll
      for (int i=0;i<4;i++){
        kreg[i] = *(const us4*)(Kn + (size_t)rr[i]*3072 + cc[i]*4);
        vreg[i] = *(const us4*)(Vn + (size_t)rr[i]*3072 + cc[i]*4);
      }
      if (t < 64) ilreg = iL[kt + 64 + t];
    }
    // softmax: s = QK^T/32, P = exp(s)*invL[k]
    float il[4];
#pragma unroll
    for (int n=0;n<4;n++) il[n] = iLs[n*16 + (l&15)];
#pragma unroll
    for (int n=0;n<4;n++){
      const int r = n*16 + (l&15);
      const int sw = (r&7)<<4;
      const short8 kf0 = *(const short8*)((char*)Klds + ((r*128 +      (l>>4)*16) ^ sw));
      const short8 kf1 = *(const short8*)((char*)Klds + ((r*128 + 64 + (l>>4)*16) ^ sw));
      f32x4 s = {};
      s = mfma16(qf[0], kf0, s);
      s = mfma16(qf[1], kf1, s);
      const int prow = w*16 + (l>>4)*4;
      const int pcol = n*16 + (l&15);
#pragma unroll
      for (int j=0;j<4;j++)
        P[(prow+j)*68 + pcol] = f2b(__expf(s[j]*0.03125f) * il[n]);
    }
    __syncthreads();                               // B2: P/VT visible
    // PV MFMA
#pragma unroll
    for (int kk=0;kk<2;kk++){
      const short8 af = *(const short8*)&P[(w*16 + (l&15))*68 + kk*32 + (l>>4)*8];
#pragma unroll
      for (int n=0;n<4;n++){
        const short8 bf = *(const short8*)&VT[(n*16 + (l&15))*66 + kk*32 + (l>>4)*8];
        acc[n] = mfma16(af, bf, acc[n]);
      }
    }
  }
  const int rowb = b*2048 + qblk*64 + w*16;
  const int colb = h*64;
#pragma unroll
  for (int n=0;n<4;n++)
#pragma unroll
    for (int j=0;j<4;j++){
      const int row = rowb + (l>>4)*4 + j;
      const int col = colb + n*16 + (l&15);
      Aout[(size_t)row*1024 + col] = f2b(acc[n][j]);
    }
}

// ---------------- Host orchestration ----------------
extern "C" void kernel_launch(void* const* d_in, const int* in_sizes, int n_in,
                              void* d_out, int out_size, void* d_ws, size_t ws_size,
                              hipStream_t stream)
{
  const float* x    = (const float*)d_in[0];
  const float* ln1g = (const float*)d_in[1];
  const float* ln1b = (const float*)d_in[2];
  const float* wq   = (const float*)d_in[3];
  const float* bq   = (const float*)d_in[4];
  const float* wk   = (const float*)d_in[5];
  const float* bk   = (const float*)d_in[6];
  const float* wv   = (const float*)d_in[7];
  const float* bv   = (const float*)d_in[8];
  const float* wo   = (const float*)d_in[9];
  const float* bo   = (const float*)d_in[10];
  const float* ln2g = (const float*)d_in[11];
  const float* ln2b = (const float*)d_in[12];
  const float* w1   = (const float*)d_in[13];
  const float* b1   = (const float*)d_in[14];
  const float* w2   = (const float*)d_in[15];
  const float* b2   = (const float*)d_in[16];
  float* out = (float*)d_out;   // reference output dtype is float32

  // Workspace layout (~72.8 MiB)
  char* ws = (char*)d_ws;
  u16*   x1      = (u16*)  (ws + 0);             // [0, 8M)   x1 / x2
  u16*   QKV     = (u16*)  (ws + 8388608);       // [8M, 32M)  -> later H1 [8M, 40M)
  u16*   H1      = (u16*)  (ws + 8388608);
  float* Lbuf    = (float*)(ws + 41943040);      // [40M, +512K)  2 partials
  u16*   Aout    = (u16*)  (ws + 42467328);      // +8M
  u16*   packbuf = (u16*)  (ws + 50855936);      // +8M
  float* inter   = (float*)(ws + 59244544);      // +16M
  float* biasqkv = (float*)(ws + 76021760);      // +12K
  float* invLb   = (float*)(ws + 76038144);      // +256K
  u16*   x2 = x1;

  pack_bias_k<<<12, 256, 0, stream>>>(bq, bk, bv, biasqkv);

  ln_k<<<4096, 256, 0, stream>>>(x, ln1g, ln1b, x1);
  pack_qkv_k<<<dim3(2,32,48), 256, 0, stream>>>(wq, wk, wv, packbuf);
  gemm_bt<0><<<dim3(24,32), 256, 0, stream>>>(x1, packbuf, biasqkv,
      nullptr, QKV, nullptr, 1024, 1024, 1024, 3072);

  attn_stats<<<1024, 256, 0, stream>>>(QKV, Lbuf);
  inv_l<<<256, 256, 0, stream>>>(Lbuf, invLb);
  attn_pv  <<<1024, 256, 0, stream>>>(QKV, invLb, Aout);

  transpose_k<<<dim3(32,32), 256, 0, stream>>>(wo, packbuf, 1024, 1024);
  gemm_bt64<1><<<dim3(16,32), 256, 0, stream>>>(Aout, packbuf, bo,
      x, nullptr, inter, 1024, 1024, 1024, 1024);

  ln_k<<<4096, 256, 0, stream>>>(inter, ln2g, ln2b, x2);

  transpose_k<<<dim3(128,32), 256, 0, stream>>>(w1, packbuf, 4096, 1024);
  gemm_bt<2><<<dim3(32,32), 256, 0, stream>>>(x2, packbuf, b1,
      nullptr, H1, nullptr, 1024, 1024, 1024, 4096);

  transpose_k<<<dim3(32,128), 256, 0, stream>>>(w2, packbuf, 1024, 4096);
  gemm_bt64<1><<<dim3(16,32), 256, 0, stream>>>(H1, packbuf, b2,
      inter, nullptr, out, 4096, 4096, 4096, 1024);
}

// Round 8
// 434.659 us; speedup vs baseline: 1.2412x; 1.0972x over previous
//
#include <hip/hip_runtime.h>
#include <hip/hip_bf16.h>

typedef unsigned short u16;
typedef __attribute__((ext_vector_type(8))) short short8;
typedef __attribute__((ext_vector_type(4))) float f32x4;
typedef __attribute__((ext_vector_type(4))) unsigned short us4;
typedef __attribute__((ext_vector_type(4))) float float4v;

#define DEV __device__ __forceinline__

DEV float b2f(u16 v){ return __uint_as_float(((unsigned)v)<<16); }
DEV u16 f2b(float f){
  unsigned u = __float_as_uint(f);
  u = u + 0x7FFFu + ((u>>16)&1u);
  return (u16)(u>>16);
}
DEV f32x4 mfma16(short8 a, short8 b, f32x4 c){
  return __builtin_amdgcn_mfma_f32_16x16x32_bf16(a, b, c, 0, 0, 0);
}
DEV void async16(const void* g, const void* l){
  __builtin_amdgcn_global_load_lds(
    (const __attribute__((address_space(1))) unsigned int*)(uintptr_t)g,
    (__attribute__((address_space(3))) unsigned int*)(unsigned int)(uintptr_t)l,
    16, 0, 0);
}

// ---------------- LayerNorm (row = one token, D=1024), fp32 in -> bf16 out ----------------
__global__ __launch_bounds__(256) void ln_k(const float* __restrict__ xin,
    const float* __restrict__ g, const float* __restrict__ bb, u16* __restrict__ y)
{
  const int row = blockIdx.x, t = threadIdx.x, l = t&63, w = t>>6;
  const float4v rr = *(const float4v*)(xin + (size_t)row*1024 + t*4);
  float v[4] = {rr[0], rr[1], rr[2], rr[3]};
  float s  = v[0]+v[1]+v[2]+v[3];
  float ss = v[0]*v[0]+v[1]*v[1]+v[2]*v[2]+v[3]*v[3];
#pragma unroll
  for (int off=32; off>=1; off>>=1){
    s  += __shfl_down(s,  off, 64);
    ss += __shfl_down(ss, off, 64);
  }
  __shared__ float rs[4], rq[4];
  if (l==0){ rs[w]=s; rq[w]=ss; }
  __syncthreads();
  const float S = rs[0]+rs[1]+rs[2]+rs[3];
  const float Q = rq[0]+rq[1]+rq[2]+rq[3];
  const float mean = S*(1.0f/1024.0f);
  const float var  = Q*(1.0f/1024.0f) - mean*mean;
  const float rstd = rsqrtf(var + 1e-5f);
  const float4v gg = *(const float4v*)(g  + t*4);
  const float4v bv = *(const float4v*)(bb + t*4);
  us4 o;
#pragma unroll
  for (int j=0;j<4;j++) o[j] = f2b((v[j]-mean)*rstd*gg[j] + bv[j]);
  *(us4*)(y + (size_t)row*1024 + t*4) = o;
}

// ---------------- Weight packing: fp32 src -> bf16 BT[N][K] ----------------
__global__ void transpose_k(const float* __restrict__ src, u16* __restrict__ dst,
                            int ldsrc, int lddst)
{
  __shared__ u16 tile[32][33];
  const int tx = threadIdx.x & 31, ty = threadIdx.x >> 5;
  const int c0 = blockIdx.x*32, r0 = blockIdx.y*32;
#pragma unroll
  for (int i=0;i<32;i+=8) tile[ty+i][tx] = f2b(src[(size_t)(r0+ty+i)*ldsrc + c0+tx]);
  __syncthreads();
#pragma unroll
  for (int i=0;i<32;i+=8) dst[(size_t)(c0+ty+i)*lddst + r0+tx] = tile[tx][ty+i];
}

// wq/wk/wv: fp32 [H=16][D=1024][E=64] -> bf16 BT[(which*1024 + h*64 + e)][d]
__global__ void pack_qkv_k(const float* __restrict__ wq, const float* __restrict__ wk,
                           const float* __restrict__ wv, u16* __restrict__ BT)
{
  __shared__ u16 tile[32][33];
  const int z = blockIdx.z, which = z>>4, h = z&15;
  const float* w = (which==0?wq:(which==1?wk:wv)) + (size_t)h*1024*64;
  u16* d = BT + (size_t)(which*1024 + h*64)*1024;
  const int tx = threadIdx.x & 31, ty = threadIdx.x >> 5;
  const int c0 = blockIdx.x*32, r0 = blockIdx.y*32;   // c over E(64), r over D(1024)
#pragma unroll
  for (int i=0;i<32;i+=8) tile[ty+i][tx] = f2b(w[(size_t)(r0+ty+i)*64 + c0+tx]);
  __syncthreads();
#pragma unroll
  for (int i=0;i<32;i+=8) d[(size_t)(c0+ty+i)*1024 + r0+tx] = tile[tx][ty+i];
}

// concat fp32 biases bq|bk|bv -> biasqkv[3072]
__global__ void pack_bias_k(const float* __restrict__ bq, const float* __restrict__ bk,
                            const float* __restrict__ bv, float* __restrict__ dst)
{
  const int t = blockIdx.x*256 + threadIdx.x;   // 0..3071
  const float* s = (t < 1024) ? bq : (t < 2048 ? bk : bv);
  dst[t] = s[t & 1023];
}

// invL[i] = 1 / (Lpart0[i] + Lpart1[i]) ; 65536 elems
__global__ __launch_bounds__(256) void inv_l(const float* __restrict__ L, float* __restrict__ invL)
{
  const int i = blockIdx.x*256 + threadIdx.x;
  invL[i] = 1.0f / (L[i] + L[i + 65536]);
}

// ---------------- GEMM, 2-phase pipelined, BK=64, T2-swizzled LDS ----------------
// C[M,N] = A[M,K](bf16) * BT[N,K](bf16)^T, tile 128 x BN (BN = 128 or 64).
// LDS layout per buffer: A[128][64] u16 then B[BN][64] u16, rows 128 B.
// Swizzle (rule #21, both-sides): global source chunk = (c ^ (row&7)),
// linear global_load_lds dest, ds_read col-byte XOR ((l&7)<<4).
// EPI: 0 = +bias -> bf16 ; 1 = +bias + f32 residual -> f32 out ; 2 = +bias + GELU -> bf16
template<int EPI, int BN>
__global__ __launch_bounds__(256) void gemm2(
    const u16* __restrict__ A, const u16* __restrict__ BT,
    const float* __restrict__ bias, const float* __restrict__ resf,
    u16* __restrict__ outb, float* __restrict__ outf,
    int K, int lda, int ldb, int ldc)
{
  constexpr int MF   = (BN==128) ? 4 : 2;        // m-fragments per wave
  constexpr int BISS = BN/32;                    // B staging issues
  __shared__ u16 smem[2][(128+BN)*64];
  const int t = threadIdx.x, l = t&63, w = t>>6;
  const int bn = blockIdx.x, bm = blockIdx.y;
  const int wr = (BN==128) ? (w>>1)*64 : w*32;
  const int wc = (BN==128) ? (w&1)*64  : 0;
  // staging source (pre-swizzled chunk) and LDS dest offsets
  const int srow = t>>3;                          // 0..31
  const int schunk = ((t&7) ^ (srow&7)) * 8;      // u16 col offset
  const u16* gA = A  + (size_t)(bm*128 + srow)*lda + schunk;
  const u16* gB = BT + (size_t)(bn*BN  + srow)*ldb + schunk;
  char* ldsA0 = (char*)&smem[0][0];
  char* ldsB0 = (char*)&smem[0][128*64];
  char* ldsA1 = (char*)&smem[1][0];
  char* ldsB1 = (char*)&smem[1][128*64];
  // ds_read offsets
  int colx[2];
#pragma unroll
  for (int kk=0;kk<2;kk++) colx[kk] = (kk*64 + (l>>4)*16) ^ ((l&7)<<4);
  int rowA[MF], rowB[4];
#pragma unroll
  for (int m=0;m<MF;m++) rowA[m] = (wr + m*16 + (l&15))*128;
#pragma unroll
  for (int n=0;n<4;n++)  rowB[n] = (wc + n*16 + (l&15))*128;

#define STAGE(bufA, bufB, kt)                                            \
  {                                                                      \
    _Pragma("unroll")                                                    \
    for (int i=0;i<4;i++)                                                \
      async16(gA + (kt) + (size_t)i*32*lda, (bufA) + i*4096 + t*16);     \
    _Pragma("unroll")                                                    \
    for (int i=0;i<BISS;i++)                                             \
      async16(gB + (kt) + (size_t)i*32*ldb, (bufB) + i*4096 + t*16);     \
  }

  f32x4 acc[MF][4] = {};
  STAGE(ldsA0, ldsB0, 0);
  __syncthreads();
  const int nt = K >> 6;
  int cur = 0;
  for (int ti = 0; ti < nt; ++ti){
    char* cA = cur ? ldsA1 : ldsA0;
    char* cB = cur ? ldsB1 : ldsB0;
    if (ti + 1 < nt){
      char* pA = cur ? ldsA0 : ldsA1;
      char* pB = cur ? ldsB0 : ldsB1;
      STAGE(pA, pB, (ti+1)*64);
    }
#pragma unroll
    for (int kk=0;kk<2;kk++){
      short8 af[MF], bf[4];
#pragma unroll
      for (int m=0;m<MF;m++) af[m] = *(const short8*)(cA + rowA[m] + colx[kk]);
#pragma unroll
      for (int n=0;n<4;n++)  bf[n] = *(const short8*)(cB + rowB[n] + colx[kk]);
#pragma unroll
      for (int m=0;m<MF;m++)
#pragma unroll
        for (int n=0;n<4;n++)
          acc[m][n] = mfma16(af[m], bf[n], acc[m][n]);
    }
    __syncthreads();      // vmcnt(0)+lgkmcnt(0) drain: next buffer staged, reads done
    cur ^= 1;
  }
#undef STAGE

  const int rowb = bm*128 + wr, colb = bn*BN + wc;
#pragma unroll
  for (int m=0;m<MF;m++)
#pragma unroll
    for (int n=0;n<4;n++){
      const int col = colb + n*16 + (l&15);
      const float bv = bias[col];
#pragma unroll
      for (int j=0;j<4;j++){
        const int row = rowb + m*16 + (l>>4)*4 + j;
        float v = acc[m][n][j] + bv;
        const size_t idx = (size_t)row*ldc + col;
        if constexpr (EPI==0)      outb[idx] = f2b(v);
        else if constexpr (EPI==1) outf[idx] = v + resf[idx];
        else                       outb[idx] = f2b(0.5f*v*(1.0f + erff(v*0.70710678118654752f)));
      }
    }
}

// ---------------- Attention ----------------
// QKV layout: [4096 tokens][3072], cols 0..1023=Q, 1024..2047=K, 2048..3071=V (col = h*64+e)
// Column softmax (over q): L[k] = sum_q exp(s[q,k]), s = Q.K^T / 32.

__global__ __launch_bounds__(256) void attn_stats(const u16* __restrict__ QKV, float* __restrict__ L)
{
  const int g = blockIdx.x;                 // 0..1023, XCD-swizzled
  const int xcd = g & 7, s_ = g >> 3;
  const int bh   = xcd*4 + (s_ & 3);
  const int kblk = (s_ >> 2) & 15;
  const int part = s_ >> 6;                 // 0/1
  const int b = bh>>4, h = bh&15;
  const u16* Qb = QKV + (size_t)b*2048*3072 + h*64;
  const u16* Kb = Qb + 1024;
  __shared__ u16 Klds[128*64];
  __shared__ float red[4][128];
  const int t = threadIdx.x, l = t&63, w = t>>6;
#pragma unroll
  for (int i=0;i<8;i++){
    const int c = t + i*256, r = c>>4, ch = c&15;
    us4 v = *(const us4*)(Kb + (size_t)(kblk*128 + r)*3072 + ch*4);
    *(us4*)((char*)Klds + ((r*128 + ch*8) ^ ((r&7)<<4))) = v;
  }
  __syncthreads();
  short8 kf[8][2];
#pragma unroll
  for (int n=0;n<8;n++){
    const int r = n*16 + (l&15);
    const int sw = (r&7)<<4;
#pragma unroll
    for (int ks=0;ks<2;ks++)
      kf[n][ks] = *(const short8*)((char*)Klds + ((r*128 + ks*64 + (l>>4)*16) ^ sw));
  }
  float Lacc[8] = {0,0,0,0,0,0,0,0};
  short8 qf[2][2], qn[2][2];
  {
    const int qb = part*1024 + w*32;
#pragma unroll
    for (int m=0;m<2;m++)
#pragma unroll
      for (int ks=0;ks<2;ks++)
        qf[m][ks] = *(const short8*)(Qb + (size_t)(qb + m*16 + (l&15))*3072 + ks*32 + (l>>4)*8);
  }
  for (int qt = 0; qt < 8; qt++){
    if (qt < 7){
      const int qb = part*1024 + (qt+1)*128 + w*32;
#pragma unroll
      for (int m=0;m<2;m++)
#pragma unroll
        for (int ks=0;ks<2;ks++)
          qn[m][ks] = *(const short8*)(Qb + (size_t)(qb + m*16 + (l&15))*3072 + ks*32 + (l>>4)*8);
    }
#pragma unroll
    for (int m=0;m<2;m++)
#pragma unroll
      for (int n=0;n<8;n++){
        f32x4 s = {};
        s = mfma16(qf[m][0], kf[n][0], s);
        s = mfma16(qf[m][1], kf[n][1], s);
#pragma unroll
        for (int j=0;j<4;j++) Lacc[n] += __expf(s[j]*0.03125f);
      }
    if (qt < 7){
#pragma unroll
      for (int m=0;m<2;m++)
#pragma unroll
        for (int ks=0;ks<2;ks++) qf[m][ks] = qn[m][ks];
    }
  }
#pragma unroll
  for (int n=0;n<8;n++){
    Lacc[n] += __shfl_xor(Lacc[n], 16, 64);
    Lacc[n] += __shfl_xor(Lacc[n], 32, 64);
  }
  if (l < 16){
#pragma unroll
    for (int n=0;n<8;n++) red[w][n*16 + l] = Lacc[n];
  }
  __syncthreads();
  if (t < 128)
    L[(size_t)part*65536 + (size_t)bh*2048 + kblk*128 + t]
        = red[0][t]+red[1][t]+red[2][t]+red[3][t];
}

// 2-barrier pipelined PV: K/V/invL prefetched to regs one tile ahead.
__global__ __launch_bounds__(256) void attn_pv(const u16* __restrict__ QKV,
    const float* __restrict__ invL, u16* __restrict__ Aout)
{
  const int g = blockIdx.x;                // 0..1023, XCD-swizzled
  const int xcd = g & 7, s_ = g >> 3;
  const int bh = xcd*4 + (s_ & 3);
  const int qblk = s_ >> 2;                // 0..31 (64 q-rows each)
  const int b = bh>>4, h = bh&15;
  const u16* Qb = QKV + (size_t)b*2048*3072 + h*64;
  const u16* Kb = Qb + 1024;
  const u16* Vb = Qb + 2048;
  const float* iL = invL + (size_t)bh*2048;
  __shared__ u16 Klds[64*64];
  __shared__ u16 VT[64*66];     // [e][k], stride 66
  __shared__ u16 P[64*68];      // [q][k], stride 68
  __shared__ float iLs[64];
  const int t = threadIdx.x, l = t&63, w = t>>6;
  short8 qf[2];
#pragma unroll
  for (int ks=0;ks<2;ks++)
    qf[ks] = *(const short8*)(Qb + (size_t)(qblk*64 + w*16 + (l&15))*3072 + ks*32 + (l>>4)*8);
  int rr[4], cc[4];
#pragma unroll
  for (int i=0;i<4;i++){ const int c = t + i*256; rr[i] = c>>4; cc[i] = c&15; }
  us4 kreg[4], vreg[4];
#pragma unroll
  for (int i=0;i<4;i++){
    kreg[i] = *(const us4*)(Kb + (size_t)rr[i]*3072 + cc[i]*4);
    vreg[i] = *(const us4*)(Vb + (size_t)rr[i]*3072 + cc[i]*4);
  }
  float ilreg = (t < 64) ? iL[t] : 0.0f;
  f32x4 acc[4] = {};
  for (int kt=0; kt<2048; kt+=64){
    // stage K (swizzled) + invL from regs (tile t)
#pragma unroll
    for (int i=0;i<4;i++)
      *(us4*)((char*)Klds + ((rr[i]*128 + cc[i]*8) ^ ((rr[i]&7)<<4))) = kreg[i];
    if (t < 64) iLs[t] = ilreg;
    __syncthreads();                               // B1: K/iL visible; prev-iter P/VT readers done
    // stage VT (transpose) from vreg (tile t)
#pragma unroll
    for (int i=0;i<4;i++){
#pragma unroll
      for (int jj=0;jj<4;jj++) VT[(cc[i]*4+jj)*66 + rr[i]] = vreg[i][jj];
    }
    // prefetch tile t+1 (latency hidden under softmax+PV below)
    if (kt + 64 < 2048){
      const u16* Kn = Kb + (size_t)(kt+64)*3072;
      const u16* Vn = Vb + (size_t)(kt+64)*3072;
#pragma unroll
      for (int i=0;i<4;i++){
        kreg[i] = *(const us4*)(Kn + (size_t)rr[i]*3072 + cc[i]*4);
        vreg[i] = *(const us4*)(Vn + (size_t)rr[i]*3072 + cc[i]*4);
      }
      if (t < 64) ilreg = iL[kt + 64 + t];
    }
    // softmax: s = QK^T/32, P = exp(s)*invL[k]
    float il[4];
#pragma unroll
    for (int n=0;n<4;n++) il[n] = iLs[n*16 + (l&15)];
#pragma unroll
    for (int n=0;n<4;n++){
      const int r = n*16 + (l&15);
      const int sw = (r&7)<<4;
      const short8 kf0 = *(const short8*)((char*)Klds + ((r*128 +      (l>>4)*16) ^ sw));
      const short8 kf1 = *(const short8*)((char*)Klds + ((r*128 + 64 + (l>>4)*16) ^ sw));
      f32x4 s = {};
      s = mfma16(qf[0], kf0, s);
      s = mfma16(qf[1], kf1, s);
      const int prow = w*16 + (l>>4)*4;
      const int pcol = n*16 + (l&15);
#pragma unroll
      for (int j=0;j<4;j++)
        P[(prow+j)*68 + pcol] = f2b(__expf(s[j]*0.03125f) * il[n]);
    }
    __syncthreads();                               // B2: P/VT visible
    // PV MFMA
#pragma unroll
    for (int kk=0;kk<2;kk++){
      const short8 af = *(const short8*)&P[(w*16 + (l&15))*68 + kk*32 + (l>>4)*8];
#pragma unroll
      for (int n=0;n<4;n++){
        const short8 bf = *(const short8*)&VT[(n*16 + (l&15))*66 + kk*32 + (l>>4)*8];
        acc[n] = mfma16(af, bf, acc[n]);
      }
    }
  }
  const int rowb = b*2048 + qblk*64 + w*16;
  const int colb = h*64;
#pragma unroll
  for (int n=0;n<4;n++)
#pragma unroll
    for (int j=0;j<4;j++){
      const int row = rowb + (l>>4)*4 + j;
      const int col = colb + n*16 + (l&15);
      Aout[(size_t)row*1024 + col] = f2b(acc[n][j]);
    }
}

// ---------------- Host orchestration ----------------
extern "C" void kernel_launch(void* const* d_in, const int* in_sizes, int n_in,
                              void* d_out, int out_size, void* d_ws, size_t ws_size,
                              hipStream_t stream)
{
  const float* x    = (const float*)d_in[0];
  const float* ln1g = (const float*)d_in[1];
  const float* ln1b = (const float*)d_in[2];
  const float* wq   = (const float*)d_in[3];
  const float* bq   = (const float*)d_in[4];
  const float* wk   = (const float*)d_in[5];
  const float* bk   = (const float*)d_in[6];
  const float* wv   = (const float*)d_in[7];
  const float* bv   = (const float*)d_in[8];
  const float* wo   = (const float*)d_in[9];
  const float* bo   = (const float*)d_in[10];
  const float* ln2g = (const float*)d_in[11];
  const float* ln2b = (const float*)d_in[12];
  const float* w1   = (const float*)d_in[13];
  const float* b1   = (const float*)d_in[14];
  const float* w2   = (const float*)d_in[15];
  const float* b2   = (const float*)d_in[16];
  float* out = (float*)d_out;   // reference output dtype is float32

  // Workspace layout (~72.8 MiB)
  char* ws = (char*)d_ws;
  u16*   x1      = (u16*)  (ws + 0);             // [0, 8M)   x1 / x2
  u16*   QKV     = (u16*)  (ws + 8388608);       // [8M, 32M)  -> later H1 [8M, 40M)
  u16*   H1      = (u16*)  (ws + 8388608);
  float* Lbuf    = (float*)(ws + 41943040);      // [40M, +512K)  2 partials
  u16*   Aout    = (u16*)  (ws + 42467328);      // +8M
  u16*   packbuf = (u16*)  (ws + 50855936);      // +8M
  float* inter   = (float*)(ws + 59244544);      // +16M
  float* biasqkv = (float*)(ws + 76021760);      // +12K
  float* invLb   = (float*)(ws + 76038144);      // +256K
  u16*   x2 = x1;

  pack_bias_k<<<12, 256, 0, stream>>>(bq, bk, bv, biasqkv);

  ln_k<<<4096, 256, 0, stream>>>(x, ln1g, ln1b, x1);
  pack_qkv_k<<<dim3(2,32,48), 256, 0, stream>>>(wq, wk, wv, packbuf);
  gemm2<0,128><<<dim3(24,32), 256, 0, stream>>>(x1, packbuf, biasqkv,
      nullptr, QKV, nullptr, 1024, 1024, 1024, 3072);

  attn_stats<<<1024, 256, 0, stream>>>(QKV, Lbuf);
  inv_l<<<256, 256, 0, stream>>>(Lbuf, invLb);
  attn_pv  <<<1024, 256, 0, stream>>>(QKV, invLb, Aout);

  transpose_k<<<dim3(32,32), 256, 0, stream>>>(wo, packbuf, 1024, 1024);
  gemm2<1,64><<<dim3(16,32), 256, 0, stream>>>(Aout, packbuf, bo,
      x, nullptr, inter, 1024, 1024, 1024, 1024);

  ln_k<<<4096, 256, 0, stream>>>(inter, ln2g, ln2b, x2);

  transpose_k<<<dim3(128,32), 256, 0, stream>>>(w1, packbuf, 4096, 1024);
  gemm2<2,128><<<dim3(32,32), 256, 0, stream>>>(x2, packbuf, b1,
      nullptr, H1, nullptr, 1024, 1024, 1024, 4096);

  transpose_k<<<dim3(32,128), 256, 0, stream>>>(w2, packbuf, 1024, 4096);
  gemm2<1,64><<<dim3(16,32), 256, 0, stream>>>(H1, packbuf, b2,
      inter, nullptr, out, 4096, 4096, 4096, 1024);
}

// Round 9
// 412.262 us; speedup vs baseline: 1.3086x; 1.0543x over previous
//
#include <hip/hip_runtime.h>
#include <hip/hip_bf16.h>

typedef unsigned short u16;
typedef __attribute__((ext_vector_type(8))) short short8;
typedef __attribute__((ext_vector_type(4))) float f32x4;
typedef __attribute__((ext_vector_type(4))) unsigned short us4;
typedef __attribute__((ext_vector_type(4))) float float4v;

#define DEV __device__ __forceinline__

DEV float b2f(u16 v){ return __uint_as_float(((unsigned)v)<<16); }
DEV u16 f2b(float f){
  unsigned u = __float_as_uint(f);
  u = u + 0x7FFFu + ((u>>16)&1u);
  return (u16)(u>>16);
}
DEV f32x4 mfma16(short8 a, short8 b, f32x4 c){
  return __builtin_amdgcn_mfma_f32_16x16x32_bf16(a, b, c, 0, 0, 0);
}
DEV void async16(const void* g, const void* l){
  __builtin_amdgcn_global_load_lds(
    (const __attribute__((address_space(1))) unsigned int*)(uintptr_t)g,
    (__attribute__((address_space(3))) unsigned int*)(unsigned int)(uintptr_t)l,
    16, 0, 0);
}

// ---------------- LayerNorm (row = one token, D=1024), fp32 in -> bf16 out ----------------
__global__ __launch_bounds__(256) void ln_k(const float* __restrict__ xin,
    const float* __restrict__ g, const float* __restrict__ bb, u16* __restrict__ y)
{
  const int row = blockIdx.x, t = threadIdx.x, l = t&63, w = t>>6;
  const float4v rr = *(const float4v*)(xin + (size_t)row*1024 + t*4);
  float v[4] = {rr[0], rr[1], rr[2], rr[3]};
  float s  = v[0]+v[1]+v[2]+v[3];
  float ss = v[0]*v[0]+v[1]*v[1]+v[2]*v[2]+v[3]*v[3];
#pragma unroll
  for (int off=32; off>=1; off>>=1){
    s  += __shfl_down(s,  off, 64);
    ss += __shfl_down(ss, off, 64);
  }
  __shared__ float rs[4], rq[4];
  if (l==0){ rs[w]=s; rq[w]=ss; }
  __syncthreads();
  const float S = rs[0]+rs[1]+rs[2]+rs[3];
  const float Q = rq[0]+rq[1]+rq[2]+rq[3];
  const float mean = S*(1.0f/1024.0f);
  const float var  = Q*(1.0f/1024.0f) - mean*mean;
  const float rstd = rsqrtf(var + 1e-5f);
  const float4v gg = *(const float4v*)(g  + t*4);
  const float4v bv = *(const float4v*)(bb + t*4);
  us4 o;
#pragma unroll
  for (int j=0;j<4;j++) o[j] = f2b((v[j]-mean)*rstd*gg[j] + bv[j]);
  *(us4*)(y + (size_t)row*1024 + t*4) = o;
}

// ---------------- Weight packing: fp32 src -> bf16 BT[N][K] ----------------
__global__ void transpose_k(const float* __restrict__ src, u16* __restrict__ dst,
                            int ldsrc, int lddst)
{
  __shared__ u16 tile[32][33];
  const int tx = threadIdx.x & 31, ty = threadIdx.x >> 5;
  const int c0 = blockIdx.x*32, r0 = blockIdx.y*32;
#pragma unroll
  for (int i=0;i<32;i+=8) tile[ty+i][tx] = f2b(src[(size_t)(r0+ty+i)*ldsrc + c0+tx]);
  __syncthreads();
#pragma unroll
  for (int i=0;i<32;i+=8) dst[(size_t)(c0+ty+i)*lddst + r0+tx] = tile[tx][ty+i];
}

// wq/wk/wv: fp32 [H=16][D=1024][E=64] -> bf16 BT[(which*1024 + h*64 + e)][d]
__global__ void pack_qkv_k(const float* __restrict__ wq, const float* __restrict__ wk,
                           const float* __restrict__ wv, u16* __restrict__ BT)
{
  __shared__ u16 tile[32][33];
  const int z = blockIdx.z, which = z>>4, h = z&15;
  const float* w = (which==0?wq:(which==1?wk:wv)) + (size_t)h*1024*64;
  u16* d = BT + (size_t)(which*1024 + h*64)*1024;
  const int tx = threadIdx.x & 31, ty = threadIdx.x >> 5;
  const int c0 = blockIdx.x*32, r0 = blockIdx.y*32;   // c over E(64), r over D(1024)
#pragma unroll
  for (int i=0;i<32;i+=8) tile[ty+i][tx] = f2b(w[(size_t)(r0+ty+i)*64 + c0+tx]);
  __syncthreads();
#pragma unroll
  for (int i=0;i<32;i+=8) d[(size_t)(c0+ty+i)*1024 + r0+tx] = tile[tx][ty+i];
}

// concat fp32 biases bq|bk|bv -> biasqkv[3072]
__global__ void pack_bias_k(const float* __restrict__ bq, const float* __restrict__ bk,
                            const float* __restrict__ bv, float* __restrict__ dst)
{
  const int t = blockIdx.x*256 + threadIdx.x;   // 0..3071
  const float* s = (t < 1024) ? bq : (t < 2048 ? bk : bv);
  dst[t] = s[t & 1023];
}

// invL[i] = 1 / (Lpart0[i] + Lpart1[i]) ; 65536 elems
__global__ __launch_bounds__(256) void inv_l(const float* __restrict__ L, float* __restrict__ invL)
{
  const int i = blockIdx.x*256 + threadIdx.x;
  invL[i] = 1.0f / (L[i] + L[i + 65536]);
}

// V-transpose with invL folded: VTg[bh][e][tok] = V[b,tok,h,e] * invL[bh][tok]
__global__ __launch_bounds__(256) void vtrans(const u16* __restrict__ QKV,
    const float* __restrict__ invL, u16* __restrict__ VTg)
{
  __shared__ u16 tile[32][33];
  __shared__ float ltile[32];
  const int t = threadIdx.x;
  const int bh = blockIdx.z, b = bh>>4, h = bh&15;
  const int tok0 = blockIdx.x*32, e0 = blockIdx.y*32;
  const u16* V = QKV + (size_t)b*2048*3072 + 2048 + h*64;
  const int tx = t&31, ty = t>>5;
  if (t < 32) ltile[t] = invL[(size_t)bh*2048 + tok0 + t];
#pragma unroll
  for (int i=0;i<32;i+=8) tile[ty+i][tx] = V[(size_t)(tok0+ty+i)*3072 + e0+tx];
  __syncthreads();
#pragma unroll
  for (int i=0;i<32;i+=8){
    const float v = b2f(tile[tx][ty+i]) * ltile[tx];
    VTg[(size_t)bh*131072 + (size_t)(e0+ty+i)*2048 + tok0+tx] = f2b(v);
  }
}

// ---------------- GEMM, 2-phase pipelined, BK=64, T2-swizzled LDS ----------------
// C[M,N] = A[M,K](bf16) * BT[N,K](bf16)^T, tile 128 x BN (BN = 128 or 64).
// EPI: 0 = +bias -> bf16 ; 1 = +bias + f32 residual -> f32 out ; 2 = +bias + GELU -> bf16
template<int EPI, int BN>
__global__ __launch_bounds__(256) void gemm2(
    const u16* __restrict__ A, const u16* __restrict__ BT,
    const float* __restrict__ bias, const float* __restrict__ resf,
    u16* __restrict__ outb, float* __restrict__ outf,
    int K, int lda, int ldb, int ldc)
{
  constexpr int MF   = (BN==128) ? 4 : 2;        // m-fragments per wave
  constexpr int BISS = BN/32;                    // B staging issues
  __shared__ u16 smem[2][(128+BN)*64];
  const int t = threadIdx.x, l = t&63, w = t>>6;
  const int bn = blockIdx.x, bm = blockIdx.y;
  const int wr = (BN==128) ? (w>>1)*64 : w*32;
  const int wc = (BN==128) ? (w&1)*64  : 0;
  const int srow = t>>3;                          // 0..31
  const int schunk = ((t&7) ^ (srow&7)) * 8;      // u16 col offset (pre-swizzled source)
  const u16* gA = A  + (size_t)(bm*128 + srow)*lda + schunk;
  const u16* gB = BT + (size_t)(bn*BN  + srow)*ldb + schunk;
  char* ldsA0 = (char*)&smem[0][0];
  char* ldsB0 = (char*)&smem[0][128*64];
  char* ldsA1 = (char*)&smem[1][0];
  char* ldsB1 = (char*)&smem[1][128*64];
  int colx[2];
#pragma unroll
  for (int kk=0;kk<2;kk++) colx[kk] = (kk*64 + (l>>4)*16) ^ ((l&7)<<4);
  int rowA[MF], rowB[4];
#pragma unroll
  for (int m=0;m<MF;m++) rowA[m] = (wr + m*16 + (l&15))*128;
#pragma unroll
  for (int n=0;n<4;n++)  rowB[n] = (wc + n*16 + (l&15))*128;

#define STAGE(bufA, bufB, kt)                                            \
  {                                                                      \
    _Pragma("unroll")                                                    \
    for (int i=0;i<4;i++)                                                \
      async16(gA + (kt) + (size_t)i*32*lda, (bufA) + i*4096 + t*16);     \
    _Pragma("unroll")                                                    \
    for (int i=0;i<BISS;i++)                                             \
      async16(gB + (kt) + (size_t)i*32*ldb, (bufB) + i*4096 + t*16);     \
  }

  f32x4 acc[MF][4] = {};
  STAGE(ldsA0, ldsB0, 0);
  __syncthreads();
  const int nt = K >> 6;
  int cur = 0;
  for (int ti = 0; ti < nt; ++ti){
    char* cA = cur ? ldsA1 : ldsA0;
    char* cB = cur ? ldsB1 : ldsB0;
    if (ti + 1 < nt){
      char* pA = cur ? ldsA0 : ldsA1;
      char* pB = cur ? ldsB0 : ldsB1;
      STAGE(pA, pB, (ti+1)*64);
    }
#pragma unroll
    for (int kk=0;kk<2;kk++){
      short8 af[MF], bf[4];
#pragma unroll
      for (int m=0;m<MF;m++) af[m] = *(const short8*)(cA + rowA[m] + colx[kk]);
#pragma unroll
      for (int n=0;n<4;n++)  bf[n] = *(const short8*)(cB + rowB[n] + colx[kk]);
#pragma unroll
      for (int m=0;m<MF;m++)
#pragma unroll
        for (int n=0;n<4;n++)
          acc[m][n] = mfma16(af[m], bf[n], acc[m][n]);
    }
    __syncthreads();
    cur ^= 1;
  }
#undef STAGE

  const int rowb = bm*128 + wr, colb = bn*BN + wc;
#pragma unroll
  for (int m=0;m<MF;m++)
#pragma unroll
    for (int n=0;n<4;n++){
      const int col = colb + n*16 + (l&15);
      const float bv = bias[col];
#pragma unroll
      for (int j=0;j<4;j++){
        const int row = rowb + m*16 + (l>>4)*4 + j;
        float v = acc[m][n][j] + bv;
        const size_t idx = (size_t)row*ldc + col;
        if constexpr (EPI==0)      outb[idx] = f2b(v);
        else if constexpr (EPI==1) outf[idx] = v + resf[idx];
        else                       outb[idx] = f2b(0.5f*v*(1.0f + erff(v*0.70710678118654752f)));
      }
    }
}

// ---------------- Attention ----------------
// QKV layout: [4096 tokens][3072], cols 0..1023=Q, 1024..2047=K, 2048..3071=V (col = h*64+e)
// Column softmax (over q): L[k] = sum_q exp(s[q,k]), s = Q.K^T / 32.

__global__ __launch_bounds__(256) void attn_stats(const u16* __restrict__ QKV, float* __restrict__ L)
{
  const int g = blockIdx.x;                 // 0..1023, XCD-swizzled
  const int xcd = g & 7, s_ = g >> 3;
  const int bh   = xcd*4 + (s_ & 3);
  const int kblk = (s_ >> 2) & 15;
  const int part = s_ >> 6;                 // 0/1
  const int b = bh>>4, h = bh&15;
  const u16* Qb = QKV + (size_t)b*2048*3072 + h*64;
  const u16* Kb = Qb + 1024;
  __shared__ u16 Klds[128*64];
  __shared__ float red[4][128];
  const int t = threadIdx.x, l = t&63, w = t>>6;
#pragma unroll
  for (int i=0;i<8;i++){
    const int c = t + i*256, r = c>>4, ch = c&15;
    us4 v = *(const us4*)(Kb + (size_t)(kblk*128 + r)*3072 + ch*4);
    *(us4*)((char*)Klds + ((r*128 + ch*8) ^ ((r&7)<<4))) = v;
  }
  __syncthreads();
  short8 kf[8][2];
#pragma unroll
  for (int n=0;n<8;n++){
    const int r = n*16 + (l&15);
    const int sw = (r&7)<<4;
#pragma unroll
    for (int ks=0;ks<2;ks++)
      kf[n][ks] = *(const short8*)((char*)Klds + ((r*128 + ks*64 + (l>>4)*16) ^ sw));
  }
  float Lacc[8] = {0,0,0,0,0,0,0,0};
  short8 qf[2][2], qn[2][2];
  {
    const int qb = part*1024 + w*32;
#pragma unroll
    for (int m=0;m<2;m++)
#pragma unroll
      for (int ks=0;ks<2;ks++)
        qf[m][ks] = *(const short8*)(Qb + (size_t)(qb + m*16 + (l&15))*3072 + ks*32 + (l>>4)*8);
  }
  for (int qt = 0; qt < 8; qt++){
    if (qt < 7){
      const int qb = part*1024 + (qt+1)*128 + w*32;
#pragma unroll
      for (int m=0;m<2;m++)
#pragma unroll
        for (int ks=0;ks<2;ks++)
          qn[m][ks] = *(const short8*)(Qb + (size_t)(qb + m*16 + (l&15))*3072 + ks*32 + (l>>4)*8);
    }
#pragma unroll
    for (int m=0;m<2;m++)
#pragma unroll
      for (int n=0;n<8;n++){
        f32x4 s = {};
        s = mfma16(qf[m][0], kf[n][0], s);
        s = mfma16(qf[m][1], kf[n][1], s);
#pragma unroll
        for (int j=0;j<4;j++) Lacc[n] += __expf(s[j]*0.03125f);
      }
    if (qt < 7){
#pragma unroll
      for (int m=0;m<2;m++)
#pragma unroll
        for (int ks=0;ks<2;ks++) qf[m][ks] = qn[m][ks];
    }
  }
#pragma unroll
  for (int n=0;n<8;n++){
    Lacc[n] += __shfl_xor(Lacc[n], 16, 64);
    Lacc[n] += __shfl_xor(Lacc[n], 32, 64);
  }
  if (l < 16){
#pragma unroll
    for (int n=0;n<8;n++) red[w][n*16 + l] = Lacc[n];
  }
  __syncthreads();
  if (t < 128)
    L[(size_t)part*65536 + (size_t)bh*2048 + kblk*128 + t]
        = red[0][t]+red[1][t]+red[2][t]+red[3][t];
}

// 2-barrier pipelined PV; V pre-transposed+pre-scaled in VTg; all LDS tiles
// [64][64] u16 with byte-XOR swizzle ((row&7)<<4) -> no conflicted scalar writes.
__global__ __launch_bounds__(256) void attn_pv(const u16* __restrict__ QKV,
    const u16* __restrict__ VTg, u16* __restrict__ Aout)
{
  const int g = blockIdx.x;                // 0..1023, XCD-swizzled
  const int xcd = g & 7, s_ = g >> 3;
  const int bh = xcd*4 + (s_ & 3);
  const int qblk = s_ >> 2;                // 0..31 (64 q-rows each)
  const int b = bh>>4, h = bh&15;
  const u16* Qb = QKV + (size_t)b*2048*3072 + h*64;
  const u16* Kb = Qb + 1024;
  const u16* Vt = VTg + (size_t)bh*131072;   // [64 e][2048 tok], invL folded
  __shared__ u16 Klds[64*64];
  __shared__ u16 Vlds[64*64];
  __shared__ u16 P[64*64];
  const int t = threadIdx.x, l = t&63, w = t>>6;
  short8 qf[2];
#pragma unroll
  for (int ks=0;ks<2;ks++)
    qf[ks] = *(const short8*)(Qb + (size_t)(qblk*64 + w*16 + (l&15))*3072 + ks*32 + (l>>4)*8);
  int rr[4], cc[4];
#pragma unroll
  for (int i=0;i<4;i++){ const int c = t + i*256; rr[i] = c>>4; cc[i] = c&15; }
  us4 kreg[4], vreg[4];
#pragma unroll
  for (int i=0;i<4;i++){
    kreg[i] = *(const us4*)(Kb + (size_t)rr[i]*3072 + cc[i]*4);
    vreg[i] = *(const us4*)(Vt + (size_t)rr[i]*2048 + cc[i]*4);
  }
  f32x4 acc[4] = {};
  for (int kt=0; kt<2048; kt+=64){
    // stage K (swizzled us4) from regs (tile t)
#pragma unroll
    for (int i=0;i<4;i++)
      *(us4*)((char*)Klds + ((rr[i]*128 + cc[i]*8) ^ ((rr[i]&7)<<4))) = kreg[i];
    __syncthreads();                               // B1
    // stage VT (swizzled us4) from regs (tile t)
#pragma unroll
    for (int i=0;i<4;i++)
      *(us4*)((char*)Vlds + ((rr[i]*128 + cc[i]*8) ^ ((rr[i]&7)<<4))) = vreg[i];
    // prefetch tile t+1 (hidden under softmax+PV)
    if (kt + 64 < 2048){
#pragma unroll
      for (int i=0;i<4;i++){
        kreg[i] = *(const us4*)(Kb + (size_t)(kt+64+rr[i])*3072 + cc[i]*4);
        vreg[i] = *(const us4*)(Vt + (size_t)rr[i]*2048 + kt+64 + cc[i]*4);
      }
    }
    // softmax numerator: P = exp(QK^T/32)  (invL already folded into VTg)
#pragma unroll
    for (int n=0;n<4;n++){
      const int r = n*16 + (l&15);
      const int sw = (r&7)<<4;
      const short8 kf0 = *(const short8*)((char*)Klds + ((r*128 +      (l>>4)*16) ^ sw));
      const short8 kf1 = *(const short8*)((char*)Klds + ((r*128 + 64 + (l>>4)*16) ^ sw));
      f32x4 s = {};
      s = mfma16(qf[0], kf0, s);
      s = mfma16(qf[1], kf1, s);
      const int prow = w*16 + (l>>4)*4;
      const int pcb  = (n*16 + (l&15))*2;
#pragma unroll
      for (int j=0;j<4;j++){
        const int pr = prow + j;
        *(u16*)((char*)P + ((pr*128 + pcb) ^ ((pr&7)<<4))) = f2b(__expf(s[j]*0.03125f));
      }
    }
    __syncthreads();                               // B2: P/VT visible
    // PV MFMA
    const int qrow = w*16 + (l&15);
    const int qsw  = (qrow&7)<<4;
#pragma unroll
    for (int kk=0;kk<2;kk++){
      const short8 af = *(const short8*)((char*)P + ((qrow*128 + kk*64 + (l>>4)*16) ^ qsw));
#pragma unroll
      for (int n=0;n<4;n++){
        const int rv = n*16 + (l&15);
        const short8 bf = *(const short8*)((char*)Vlds + ((rv*128 + kk*64 + (l>>4)*16) ^ ((rv&7)<<4)));
        acc[n] = mfma16(af, bf, acc[n]);
      }
    }
  }
  const int rowb = b*2048 + qblk*64 + w*16;
  const int colb = h*64;
#pragma unroll
  for (int n=0;n<4;n++)
#pragma unroll
    for (int j=0;j<4;j++){
      const int row = rowb + (l>>4)*4 + j;
      const int col = colb + n*16 + (l&15);
      Aout[(size_t)row*1024 + col] = f2b(acc[n][j]);
    }
}

// ---------------- Host orchestration ----------------
extern "C" void kernel_launch(void* const* d_in, const int* in_sizes, int n_in,
                              void* d_out, int out_size, void* d_ws, size_t ws_size,
                              hipStream_t stream)
{
  const float* x    = (const float*)d_in[0];
  const float* ln1g = (const float*)d_in[1];
  const float* ln1b = (const float*)d_in[2];
  const float* wq   = (const float*)d_in[3];
  const float* bq   = (const float*)d_in[4];
  const float* wk   = (const float*)d_in[5];
  const float* bk   = (const float*)d_in[6];
  const float* wv   = (const float*)d_in[7];
  const float* bv   = (const float*)d_in[8];
  const float* wo   = (const float*)d_in[9];
  const float* bo   = (const float*)d_in[10];
  const float* ln2g = (const float*)d_in[11];
  const float* ln2b = (const float*)d_in[12];
  const float* w1   = (const float*)d_in[13];
  const float* b1   = (const float*)d_in[14];
  const float* w2   = (const float*)d_in[15];
  const float* b2   = (const float*)d_in[16];
  float* out = (float*)d_out;   // reference output dtype is float32

  // Workspace layout (~80.8 MiB)
  char* ws = (char*)d_ws;
  u16*   x1      = (u16*)  (ws + 0);             // [0, 8M)   x1 / x2
  u16*   QKV     = (u16*)  (ws + 8388608);       // [8M, 32M)  -> later H1 [8M, 40M)
  u16*   H1      = (u16*)  (ws + 8388608);
  float* Lbuf    = (float*)(ws + 41943040);      // [40M, +512K)  2 partials
  u16*   Aout    = (u16*)  (ws + 42467328);      // +8M
  u16*   packbuf = (u16*)  (ws + 50855936);      // +8M
  float* inter   = (float*)(ws + 59244544);      // +16M
  float* biasqkv = (float*)(ws + 76021760);      // +12K
  float* invLb   = (float*)(ws + 76038144);      // +256K
  u16*   VTg     = (u16*)  (ws + 76300288);      // +8M
  u16*   x2 = x1;

  pack_bias_k<<<12, 256, 0, stream>>>(bq, bk, bv, biasqkv);

  ln_k<<<4096, 256, 0, stream>>>(x, ln1g, ln1b, x1);
  pack_qkv_k<<<dim3(2,32,48), 256, 0, stream>>>(wq, wk, wv, packbuf);
  gemm2<0,128><<<dim3(24,32), 256, 0, stream>>>(x1, packbuf, biasqkv,
      nullptr, QKV, nullptr, 1024, 1024, 1024, 3072);

  attn_stats<<<1024, 256, 0, stream>>>(QKV, Lbuf);
  inv_l<<<256, 256, 0, stream>>>(Lbuf, invLb);
  vtrans<<<dim3(64,2,32), 256, 0, stream>>>(QKV, invLb, VTg);
  attn_pv<<<1024, 256, 0, stream>>>(QKV, VTg, Aout);

  transpose_k<<<dim3(32,32), 256, 0, stream>>>(wo, packbuf, 1024, 1024);
  gemm2<1,64><<<dim3(16,32), 256, 0, stream>>>(Aout, packbuf, bo,
      x, nullptr, inter, 1024, 1024, 1024, 1024);

  ln_k<<<4096, 256, 0, stream>>>(inter, ln2g, ln2b, x2);

  transpose_k<<<dim3(128,32), 256, 0, stream>>>(w1, packbuf, 4096, 1024);
  gemm2<2,128><<<dim3(32,32), 256, 0, stream>>>(x2, packbuf, b1,
      nullptr, H1, nullptr, 1024, 1024, 1024, 4096);

  transpose_k<<<dim3(32,128), 256, 0, stream>>>(w2, packbuf, 1024, 4096);
  gemm2<1,64><<<dim3(16,32), 256, 0, stream>>>(H1, packbuf, b2,
      inter, nullptr, out, 4096, 4096, 4096, 1024);
}